// Round 10
// baseline (1881.720 us; speedup 1.0000x reference)
//
#include <hip/hip_runtime.h>
#include <math.h>

#define LNUM 6
#define HNUM 12
#define CDIM 768
#define VDIM 50257
#define BDIM 4
#define TDIM 1024
#define NTOK 4096   // B*T

typedef __bf16 bf16;
typedef __bf16 bf16x8 __attribute__((ext_vector_type(8)));
typedef float  floatx4 __attribute__((ext_vector_type(4)));
typedef unsigned int u32;

// async global->LDS, 16B per lane. LDS dest must be wave-uniform base; HW adds lane*16.
__device__ inline void gload16(const bf16* gsrc, bf16* lds) {
  __builtin_amdgcn_global_load_lds(
      (const __attribute__((address_space(1))) u32*)gsrc,
      (__attribute__((address_space(3))) u32*)lds, 16, 0, 0);
}

// ---------------- fp32 -> bf16 bulk convert (wte) ----------------
__global__ void k_cvt_bf16(const float* __restrict__ in, bf16* __restrict__ out, long n) {
  long i = ((long)blockIdx.x * blockDim.x + threadIdx.x) * 4;
  long stride = (long)gridDim.x * blockDim.x * 4;
  for (; i < n; i += stride) {
    float4 v = *reinterpret_cast<const float4*>(in + i);
    bf16 b0 = (bf16)v.x, b1 = (bf16)v.y, b2 = (bf16)v.z, b3 = (bf16)v.w;
    ushort4 pk;
    pk.x = __builtin_bit_cast(unsigned short, b0);
    pk.y = __builtin_bit_cast(unsigned short, b1);
    pk.z = __builtin_bit_cast(unsigned short, b2);
    pk.w = __builtin_bit_cast(unsigned short, b3);
    *reinterpret_cast<ushort4*>(out + i) = pk;
  }
}

// -------- batched transpose+convert for ALL layer weights (one launch) --------
#define TILES_QKV  1728
#define TILES_PROJ 576
#define TILES_FC   2304
#define TILES_FCP  2304
#define TILES_LAYER (TILES_QKV + TILES_PROJ + TILES_FC + TILES_FCP)

__global__ __launch_bounds__(256) void k_trans_all(
    const float* __restrict__ qkv_w, const float* __restrict__ proj_w,
    const float* __restrict__ fc_w, const float* __restrict__ fcp_w,
    bf16* __restrict__ wq, bf16* __restrict__ wp,
    bf16* __restrict__ wf, bf16* __restrict__ wfp) {
  __shared__ float tile[32][33];
  int bid = blockIdx.x;
  int layer = bid / TILES_LAYER, r = bid % TILES_LAYER;
  const float* src; bf16* dst; int K, N, tx, ty;
  if (r < TILES_QKV) {
    src = qkv_w + (size_t)layer * CDIM * 3 * CDIM; dst = wq + (size_t)layer * CDIM * 3 * CDIM;
    K = CDIM; N = 3 * CDIM; tx = r % 72; ty = r / 72;
  } else if (r < TILES_QKV + TILES_PROJ) {
    r -= TILES_QKV;
    src = proj_w + (size_t)layer * CDIM * CDIM; dst = wp + (size_t)layer * CDIM * CDIM;
    K = CDIM; N = CDIM; tx = r % 24; ty = r / 24;
  } else if (r < TILES_QKV + TILES_PROJ + TILES_FC) {
    r -= TILES_QKV + TILES_PROJ;
    src = fc_w + (size_t)layer * CDIM * 4 * CDIM; dst = wf + (size_t)layer * CDIM * 4 * CDIM;
    K = CDIM; N = 4 * CDIM; tx = r % 96; ty = r / 96;
  } else {
    r -= TILES_QKV + TILES_PROJ + TILES_FC;
    src = fcp_w + (size_t)layer * 4 * CDIM * CDIM; dst = wfp + (size_t)layer * 4 * CDIM * CDIM;
    K = 4 * CDIM; N = CDIM; tx = r % 24; ty = r / 24;
  }
  int n0 = tx * 32, k0 = ty * 32;
  int nx = threadIdx.x & 31, tyy = threadIdx.x >> 5;
  #pragma unroll
  for (int p = 0; p < 4; ++p) {
    int k = tyy + p * 8;
    tile[k][nx] = src[(size_t)(k0 + k) * N + n0 + nx];
  }
  __syncthreads();
  #pragma unroll
  for (int p = 0; p < 4; ++p) {
    int n = tyy + p * 8;
    dst[(size_t)(n0 + n) * K + k0 + nx] = (bf16)tile[nx][n];
  }
}

// ---------------- embedding ----------------
__global__ void k_embed(const int* __restrict__ idx, const float* __restrict__ wte,
                        const float* __restrict__ wpe, float* __restrict__ x) {
  int tok = blockIdx.x;
  int t = tok & (TDIM - 1);
  int id = idx[tok];
  const float* a = wte + (size_t)id * CDIM;
  const float* p = wpe + (size_t)t * CDIM;
  float* o = x + (size_t)tok * CDIM;
  for (int c = threadIdx.x; c < CDIM; c += 256) o[c] = a[c] + p[c];
}

// ---------------- layernorm: fp32 in -> bf16 out ----------------
__global__ __launch_bounds__(256) void k_layernorm(const float* __restrict__ x,
    const float* __restrict__ sc, const float* __restrict__ bi, bf16* __restrict__ out) {
  __shared__ float red[8];
  int row = blockIdx.x;
  const float* xr = x + (size_t)row * CDIM;
  int t = threadIdx.x;
  float v0 = xr[t], v1 = xr[t + 256], v2 = xr[t + 512];
  float s = v0 + v1 + v2;
  #pragma unroll
  for (int o = 32; o > 0; o >>= 1) s += __shfl_down(s, o);
  if ((t & 63) == 0) red[t >> 6] = s;
  __syncthreads();
  float mean = (red[0] + red[1] + red[2] + red[3]) * (1.0f / CDIM);
  float d0 = v0 - mean, d1 = v1 - mean, d2 = v2 - mean;
  float q = d0 * d0 + d1 * d1 + d2 * d2;
  #pragma unroll
  for (int o = 32; o > 0; o >>= 1) q += __shfl_down(q, o);
  if ((t & 63) == 0) red[4 + (t >> 6)] = q;
  __syncthreads();
  float var = (red[4] + red[5] + red[6] + red[7]) * (1.0f / CDIM);
  float rs = rsqrtf(var + 1e-5f);
  bf16* orow = out + (size_t)row * CDIM;
  orow[t]       = (bf16)(d0 * rs * sc[t]       + bi[t]);
  orow[t + 256] = (bf16)(d1 * rs * sc[t + 256] + bi[t + 256]);
  orow[t + 512] = (bf16)(d2 * rs * sc[t + 512] + bi[t + 512]);
}

__device__ inline float gelu_f(float x) {
  float x3 = x * x * x;
  return 0.5f * x * (1.0f + tanhf(0.7978845608028654f * (x + 0.044715f * x3)));
}

// ================= deep-pipelined 256x256 BK=32 logits GEMM =================
// A: 3 LDS bufs (lead 2), B: 4 bufs (lead 3); regular 16B stores (nt reverted: write-amp).
__global__ __launch_bounds__(512, 1) void k_gemm_logits(
    const bf16* __restrict__ A, const bf16* __restrict__ Bt,
    float* __restrict__ Cf, int N, int K) {
  __shared__ __align__(16) bf16 smem[7 * 8192];
  bf16* Bs = smem;
  bf16* As = smem + 4 * 8192;
  const int nwg = gridDim.x;
  const int id = blockIdx.x;
  const int swz = (id & 7) * (nwg >> 3) + (id >> 3);
  const int m0 = (swz & 15) * 256;
  const int n0 = (swz >> 4) * 256;
  const int tid = threadIdx.x, lane = tid & 63, wave = tid >> 6;
  const int wr = wave >> 2, wc = wave & 3;
  const int g = lane >> 4, r16 = lane & 15;
  const int numK = K >> 5;
  const int wsl = wave * 512;

  const int srow = wave * 16 + (lane >> 2);
  const int scol = ((lane & 3) ^ ((lane >> 3) & 3)) * 8;   // T2 source permute
  const bf16* at  = A  + (size_t)(m0 + srow) * K + scol;
  const bf16* at1 = A  + (size_t)(m0 + srow + 128) * K + scol;
  const bf16* bt  = Bt + (size_t)(n0 + srow) * K + scol;
  const bf16* bt1 = Bt + (size_t)(n0 + srow + 128) * K + scol;
  const int sw = (g ^ ((r16 >> 1) & 3)) * 8;               // T2 read XOR
  const int a_off = (wr * 128 + r16) * 32 + sw;
  const int b_off = (wc * 64 + r16) * 32 + sw;

  floatx4 acc[8][4] = {};

#define STBd(s0, s1, pb) do { gload16((s0), Bs + (pb) * 8192 + wsl); \
                              gload16((s1), Bs + (pb) * 8192 + wsl + 4096); } while (0)
#define STAd(s0, s1, pb) do { gload16((s0), As + (pb) * 8192 + wsl); \
                              gload16((s1), As + (pb) * 8192 + wsl + 4096); } while (0)

  STBd(bt,      bt1,      0);
  STAd(at,      at1,      0);
  STBd(bt + 32, bt1 + 32, 1);
  STAd(at + 32, at1 + 32, 1);
  STBd(bt + 64, bt1 + 64, 2);
  asm volatile("s_waitcnt vmcnt(6)" ::: "memory");
  __builtin_amdgcn_s_barrier();

  for (int t = 0; t < numK; ++t) {
    const int ab = t % 3, bb = t & 3;
    bf16x8 af[4], bfr[4];

    // ---- phase 0 ----
    #pragma unroll
    for (int j = 0; j < 4; ++j) bfr[j] = *(const bf16x8*)&Bs[bb * 8192 + b_off + j * 512];
    #pragma unroll
    for (int i = 0; i < 4; ++i) af[i] = *(const bf16x8*)&As[ab * 8192 + a_off + i * 512];
    if (t + 2 < numK) STAd(at + 64, at1 + 64, (t + 2) % 3);
    __builtin_amdgcn_s_barrier();
    asm volatile("s_waitcnt lgkmcnt(0)" ::: "memory");
    __builtin_amdgcn_s_setprio(1);
    #pragma unroll
    for (int i = 0; i < 4; ++i)
      #pragma unroll
      for (int j = 0; j < 4; ++j)
        acc[i][j] = __builtin_amdgcn_mfma_f32_16x16x32_bf16(af[i], bfr[j], acc[i][j], 0, 0, 0);
    __builtin_amdgcn_s_setprio(0);
    __builtin_amdgcn_s_barrier();

    // ---- phase 1 ----
    #pragma unroll
    for (int i = 0; i < 4; ++i) af[i] = *(const bf16x8*)&As[ab * 8192 + a_off + (i + 4) * 512];
    if (t + 3 < numK) STBd(bt + 96, bt1 + 96, (t + 3) & 3);
    __builtin_amdgcn_s_barrier();
    asm volatile("s_waitcnt lgkmcnt(0)" ::: "memory");
    __builtin_amdgcn_s_setprio(1);
    #pragma unroll
    for (int i = 0; i < 4; ++i)
      #pragma unroll
      for (int j = 0; j < 4; ++j)
        acc[i + 4][j] = __builtin_amdgcn_mfma_f32_16x16x32_bf16(af[i], bfr[j], acc[i + 4][j], 0, 0, 0);
    __builtin_amdgcn_s_setprio(0);
    if (t + 3 < numK)      { asm volatile("s_waitcnt vmcnt(6)" ::: "memory"); }
    else if (t + 2 < numK) { asm volatile("s_waitcnt vmcnt(4)" ::: "memory"); }
    else                   { asm volatile("s_waitcnt vmcnt(0)" ::: "memory"); }
    __builtin_amdgcn_s_barrier();

    at += 32; at1 += 32; bt += 32; bt1 += 32;
  }
#undef STBd
#undef STAd

  // epilogue: LDS transpose -> contiguous 16B regular stores
  float* sb = reinterpret_cast<float*>(smem) + wave * 1088;  // 16 rows x 68
  const int seg = lane & 15, rq = lane >> 4;
  const int mrow_base = m0 + wr * 128;
  const int ncol_base = n0 + wc * 64;
  #pragma unroll
  for (int mf = 0; mf < 8; ++mf) {
    #pragma unroll
    for (int nf = 0; nf < 4; ++nf) {
      #pragma unroll
      for (int q = 0; q < 4; ++q)
        sb[(g * 4 + q) * 68 + nf * 16 + r16] = acc[mf][nf][q];
    }
    #pragma unroll
    for (int pz = 0; pz < 4; ++pz) {
      int row = rq + pz * 4;
      floatx4 v = *reinterpret_cast<const floatx4*>(&sb[row * 68 + seg * 4]);
      int m = mrow_base + mf * 16 + row;
      int n = ncol_base + seg * 4;
      if (n + 4 <= N) {
        __builtin_memcpy(&Cf[(size_t)m * N + n], &v, 16);
      } else {
        #pragma unroll
        for (int e = 0; e < 4; ++e)
          if (n + e < N) Cf[(size_t)m * N + n + e] = v[e];
      }
    }
  }
}

// ================= TBMx256 BK=32 pipelined MFMA GEMM (qkv / fc) =================
template<int TBM, int EPI>   // EPI: 3 +bias+gelu ->bf16, 4 +bias ->bf16
__global__ __launch_bounds__(512, 1) void k_gemm8(
    const bf16* __restrict__ A, const bf16* __restrict__ Bt,
    const float* __restrict__ bias,
    float* __restrict__ Cf, bf16* __restrict__ Cb,
    int N, int K) {
  constexpr int MI = TBM / 32;
  constexpr int MH = MI / 2;
  constexpr int MTILES = 4096 / TBM;
  __shared__ __align__(16) bf16 smem[2 * 8192 + 2 * TBM * 32];
  bf16* Bs = smem;
  bf16* As = smem + 2 * 8192;
  const int nwg = gridDim.x;
  const int id = blockIdx.x;
  const int swz = (id & 7) * (nwg >> 3) + (id >> 3);
  const int m0 = (swz % MTILES) * TBM;
  const int n0 = (swz / MTILES) * 256;
  const int tid = threadIdx.x, lane = tid & 63, wave = tid >> 6;
  const int wr = wave >> 2, wc = wave & 3;
  const int g = lane >> 4, r16 = lane & 15;
  const int numK = K >> 5;
  const int wsl = wave * 512;

  const int srow = wave * 16 + (lane >> 2);
  const int scol = ((lane & 3) ^ ((lane >> 3) & 3)) * 8;
  const bf16* at  = A  + (size_t)(m0 + srow) * K + scol;
  const bf16* at1 = A  + (size_t)(m0 + srow + 128) * K + scol;
  const bf16* bt  = Bt + (size_t)(n0 + srow) * K + scol;
  const bf16* bt1 = Bt + (size_t)(n0 + srow + 128) * K + scol;
  const int sw = (g ^ ((r16 >> 1) & 3)) * 8;
  const int a_off = (wr * (TBM / 2) + r16) * 32 + sw;
  const int b_off = (wc * 64 + r16) * 32 + sw;

  floatx4 acc[MI][4] = {};

#define STB(s0, s1, pb) do { gload16((s0), Bs + (pb) * 8192 + wsl); \
                             gload16((s1), Bs + (pb) * 8192 + wsl + 4096); } while (0)
#define STA(s0, s1, pb) do { gload16((s0), As + (pb) * TBM * 32 + wsl); \
                             if constexpr (TBM == 256) gload16((s1), As + (pb) * TBM * 32 + wsl + 4096); } while (0)

  STB(bt, bt1, 0);
  STA(at, at1, 0);
  STB(bt + 32, bt1 + 32, 1);
  asm volatile("s_waitcnt vmcnt(2)" ::: "memory");
  __builtin_amdgcn_s_barrier();

  for (int t = 0; t < numK; ++t) {
    const int p = t & 1, pn = p ^ 1;
    bf16x8 af[MH], bfr[4];

    #pragma unroll
    for (int j = 0; j < 4; ++j) bfr[j] = *(const bf16x8*)&Bs[p * 8192 + b_off + j * 512];
    #pragma unroll
    for (int i = 0; i < MH; ++i) af[i] = *(const bf16x8*)&As[p * TBM * 32 + a_off + i * 512];
    if (t + 1 < numK) STA(at + 32, at1 + 32, pn);
    __builtin_amdgcn_s_barrier();
    asm volatile("s_waitcnt lgkmcnt(0)" ::: "memory");
    __builtin_amdgcn_s_setprio(1);
    #pragma unroll
    for (int i = 0; i < MH; ++i)
      #pragma unroll
      for (int j = 0; j < 4; ++j)
        acc[i][j] = __builtin_amdgcn_mfma_f32_16x16x32_bf16(af[i], bfr[j], acc[i][j], 0, 0, 0);
    __builtin_amdgcn_s_setprio(0);
    __builtin_amdgcn_s_barrier();

    #pragma unroll
    for (int i = 0; i < MH; ++i) af[i] = *(const bf16x8*)&As[p * TBM * 32 + a_off + (i + MH) * 512];
    if (t + 2 < numK) STB(bt + 64, bt1 + 64, p);
    __builtin_amdgcn_s_barrier();
    asm volatile("s_waitcnt lgkmcnt(0)" ::: "memory");
    __builtin_amdgcn_s_setprio(1);
    #pragma unroll
    for (int i = 0; i < MH; ++i)
      #pragma unroll
      for (int j = 0; j < 4; ++j)
        acc[i + MH][j] = __builtin_amdgcn_mfma_f32_16x16x32_bf16(af[i], bfr[j], acc[i + MH][j], 0, 0, 0);
    __builtin_amdgcn_s_setprio(0);
    if (t + 2 < numK) { asm volatile("s_waitcnt vmcnt(2)" ::: "memory"); }
    else              { asm volatile("s_waitcnt vmcnt(0)" ::: "memory"); }
    __builtin_amdgcn_s_barrier();

    at += 32; at1 += 32; bt += 32; bt1 += 32;
  }
#undef STB
#undef STA

  bf16* sb = smem + wave * 1152;
  const int rr_rd = lane & 15, seg = lane >> 4;
  const int nb = n0 + wc * 64 + r16;
  float bv[4];
  #pragma unroll
  for (int j = 0; j < 4; ++j) bv[j] = bias[nb + j * 16];
  #pragma unroll
  for (int mf = 0; mf < MI; ++mf) {
    #pragma unroll
    for (int j = 0; j < 4; ++j) {
      #pragma unroll
      for (int q = 0; q < 4; ++q) {
        float v = acc[mf][j][q] + bv[j];
        if (EPI == 3) v = gelu_f(v);
        sb[(g * 4 + q) * 72 + j * 16 + r16] = (bf16)v;
      }
    }
    bf16x8 o0 = *(const bf16x8*)&sb[rr_rd * 72 + seg * 16];
    bf16x8 o1 = *(const bf16x8*)&sb[rr_rd * 72 + seg * 16 + 8];
    size_t orow = (size_t)(m0 + wr * (TBM / 2) + mf * 16 + rr_rd) * N + (n0 + wc * 64 + seg * 16);
    *(bf16x8*)&Cb[orow] = o0;
    *(bf16x8*)&Cb[orow + 8] = o1;
  }
}

// ================= 128x128 BK=32 pipelined GEMM, 4 waves (proj / fcp) =================
// bias + residual add, f32 in-place output. Scalar f32 stores: 16 lanes cover one
// aligned 64B line (N=768), so they coalesce fully.
__global__ __launch_bounds__(256, 1) void k_gemmp(
    const bf16* __restrict__ A, const bf16* __restrict__ Bt,
    const float* __restrict__ bias, float* __restrict__ Cf,
    int N, int K) {
  __shared__ __align__(16) bf16 smem[4 * 4096];
  bf16* Bs = smem;            // [2][4096]
  bf16* As = smem + 2 * 4096; // [2][4096]
  const int nwg = gridDim.x;  // 192, %8==0
  const int id = blockIdx.x;
  const int swz = (id & 7) * (nwg >> 3) + (id >> 3);
  const int m0 = (swz & 31) * 128;   // 32 m-tiles
  const int n0 = (swz >> 5) * 128;
  const int tid = threadIdx.x, lane = tid & 63, wave = tid >> 6;
  const int wr = wave >> 1, wc = wave & 1;   // 2M x 2N
  const int g = lane >> 4, r16 = lane & 15;
  const int numK = K >> 5;
  const int wsl = wave * 512;

  const int srow = wave * 16 + (lane >> 2);           // rows 0..63
  const int scol = ((lane & 3) ^ ((lane >> 3) & 3)) * 8;
  const bf16* at  = A  + (size_t)(m0 + srow) * K + scol;
  const bf16* at1 = A  + (size_t)(m0 + srow + 64) * K + scol;
  const bf16* bt  = Bt + (size_t)(n0 + srow) * K + scol;
  const bf16* bt1 = Bt + (size_t)(n0 + srow + 64) * K + scol;
  const int sw = (g ^ ((r16 >> 1) & 3)) * 8;
  const int a_off = (wr * 64 + r16) * 32 + sw;
  const int b_off = (wc * 64 + r16) * 32 + sw;

  floatx4 acc[4][4] = {};

#define STBp(s0, s1, pb) do { gload16((s0), Bs + (pb) * 4096 + wsl); \
                              gload16((s1), Bs + (pb) * 4096 + 2048 + wsl); } while (0)
#define STAp(s0, s1, pb) do { gload16((s0), As + (pb) * 4096 + wsl); \
                              gload16((s1), As + (pb) * 4096 + 2048 + wsl); } while (0)

  STBp(bt, bt1, 0);
  STAp(at, at1, 0);
  STBp(bt + 32, bt1 + 32, 1);
  asm volatile("s_waitcnt vmcnt(2)" ::: "memory");
  __builtin_amdgcn_s_barrier();

  for (int t = 0; t < numK; ++t) {
    const int p = t & 1, pn = p ^ 1;
    bf16x8 af[2], bfr[4];

    // ---- phase 0: mgroup 0 ----
    #pragma unroll
    for (int j = 0; j < 4; ++j) bfr[j] = *(const bf16x8*)&Bs[p * 4096 + b_off + j * 512];
    #pragma unroll
    for (int i = 0; i < 2; ++i) af[i] = *(const bf16x8*)&As[p * 4096 + a_off + i * 512];
    if (t + 1 < numK) STAp(at + 32, at1 + 32, pn);
    __builtin_amdgcn_s_barrier();
    asm volatile("s_waitcnt lgkmcnt(0)" ::: "memory");
    __builtin_amdgcn_s_setprio(1);
    #pragma unroll
    for (int i = 0; i < 2; ++i)
      #pragma unroll
      for (int j = 0; j < 4; ++j)
        acc[i][j] = __builtin_amdgcn_mfma_f32_16x16x32_bf16(af[i], bfr[j], acc[i][j], 0, 0, 0);
    __builtin_amdgcn_s_setprio(0);
    __builtin_amdgcn_s_barrier();

    // ---- phase 1: mgroup 1 ----
    #pragma unroll
    for (int i = 0; i < 2; ++i) af[i] = *(const bf16x8*)&As[p * 4096 + a_off + (i + 2) * 512];
    if (t + 2 < numK) STBp(bt + 64, bt1 + 64, p);
    __builtin_amdgcn_s_barrier();
    asm volatile("s_waitcnt lgkmcnt(0)" ::: "memory");
    __builtin_amdgcn_s_setprio(1);
    #pragma unroll
    for (int i = 0; i < 2; ++i)
      #pragma unroll
      for (int j = 0; j < 4; ++j)
        acc[i + 2][j] = __builtin_amdgcn_mfma_f32_16x16x32_bf16(af[i], bfr[j], acc[i + 2][j], 0, 0, 0);
    __builtin_amdgcn_s_setprio(0);
    if (t + 2 < numK) { asm volatile("s_waitcnt vmcnt(2)" ::: "memory"); }
    else              { asm volatile("s_waitcnt vmcnt(0)" ::: "memory"); }
    __builtin_amdgcn_s_barrier();

    at += 32; at1 += 32; bt += 32; bt1 += 32;
  }
#undef STBp
#undef STAp

  // epilogue: bias + residual, scalar f32 (16 lanes = one aligned 64B line)
  const int mb = m0 + wr * 64 + g * 4;
  const int nb = n0 + wc * 64 + r16;
  #pragma unroll
  for (int j = 0; j < 4; ++j) {
    int n = nb + j * 16;
    float bv = bias[n];
    #pragma unroll
    for (int i = 0; i < 4; ++i) {
      #pragma unroll
      for (int q = 0; q < 4; ++q) {
        int m = mb + i * 16 + q;
        size_t o = (size_t)m * N + n;
        Cf[o] = Cf[o] + acc[i][j][q] + bv;
      }
    }
  }
}

// ---------------- V transpose: qkv_bf V-part -> vt[bh][d][t] bf16 ----------------
__global__ __launch_bounds__(256) void k_vtrans(const bf16* __restrict__ qkv, bf16* __restrict__ vt) {
  __shared__ bf16 tile[64][72];
  int bh = blockIdx.x, t0 = blockIdx.y * 64;
  int b = bh / HNUM, h = bh % HNUM;
  int tid = threadIdx.x;
  int r8 = tid >> 3, s8 = tid & 7;
  #pragma unroll
  for (int p = 0; p < 2; ++p) {
    int row = p * 32 + r8;
    uint4 v = *reinterpret_cast<const uint4*>(
        qkv + (size_t)(b * TDIM + t0 + row) * (3 * CDIM) + 2 * CDIM + h * 64 + s8 * 8);
    *reinterpret_cast<uint4*>(&tile[row][s8 * 8]) = v;
  }
  __syncthreads();
  int d = tid >> 2, q4 = tid & 3;
  #pragma unroll
  for (int half = 0; half < 2; ++half) {
    int t = q4 * 16 + half * 8;
    bf16x8 o;
    #pragma unroll
    for (int u = 0; u < 8; ++u) o[u] = tile[t + u][d];
    *reinterpret_cast<bf16x8*>(vt + (size_t)bh * (64 * TDIM) + (size_t)d * TDIM + t0 + t) = o;
  }
}

// ---------------- MFMA flash attention, QBLK=128, 8 waves ----------------
__global__ __launch_bounds__(512) void k_attn(const bf16* __restrict__ qkv,
                                              const bf16* __restrict__ vt,
                                              bf16* __restrict__ y) {
  __shared__ __align__(16) bf16 Ks[64 * 64];
  __shared__ __align__(16) bf16 Vs[64 * 64];
  __shared__ __align__(16) bf16 Ps[128 * 64];
  const int bh = blockIdx.x, qt = blockIdx.y;    // 128-row q tile
  const int b = bh / HNUM, h = bh % HNUM;
  const int tid = threadIdx.x, lane = tid & 63, wave = tid >> 6;
  const int g = lane >> 4, r16 = lane & 15;
  const int w16 = wave * 16;                     // 0..112
  const int qtb = qt * 128;
  const int r8 = tid >> 3, s8 = tid & 7;         // 512 thr: rows 0..63 single pass

  bf16x8 qf[2];
  {
    const bf16* qsrc = qkv + (size_t)(b * TDIM + qtb + w16 + r16) * (3 * CDIM) + h * 64 + g * 8;
    qf[0] = *reinterpret_cast<const bf16x8*>(qsrc);
    qf[1] = *reinterpret_cast<const bf16x8*>(qsrc + 32);
  }

  float m_r[4], l_r[4];
  floatx4 yacc[4] = {};
  #pragma unroll
  for (int q = 0; q < 4; ++q) { m_r[q] = -1e30f; l_r[q] = 0.f; }

  const int ktmax = 2 * qt + 1;
  const int wave_qmax = qtb + w16 + 15;          // max q-row this wave owns

  for (int kt = 0; kt <= ktmax; ++kt) {
    __syncthreads();
    {
      int row = r8;
      uint4 kv = *reinterpret_cast<const uint4*>(
          qkv + (size_t)(b * TDIM + kt * 64 + row) * (3 * CDIM) + CDIM + h * 64 + s8 * 8);
      *reinterpret_cast<uint4*>(&Ks[row * 64 + ((s8 ^ (row & 7)) * 8)]) = kv;
      uint4 vv = *reinterpret_cast<const uint4*>(
          vt + (size_t)bh * (64 * TDIM) + (size_t)row * TDIM + kt * 64 + s8 * 8);
      *reinterpret_cast<uint4*>(&Vs[row * 64 + ((s8 ^ (row & 7)) * 8)]) = vv;
    }
    __syncthreads();
    if (kt * 64 > wave_qmax) continue;           // fully-masked wave: barriers done, skip compute

    floatx4 sa[4] = {};
    #pragma unroll
    for (int c = 0; c < 2; ++c) {
      bf16x8 kf[4];
      #pragma unroll
      for (int j = 0; j < 4; ++j) {
        int krow = j * 16 + r16;
        kf[j] = *reinterpret_cast<const bf16x8*>(&Ks[krow * 64 + (((g + 4 * c) ^ (krow & 7)) * 8)]);
      }
      #pragma unroll
      for (int j = 0; j < 4; ++j)
        sa[j] = __builtin_amdgcn_mfma_f32_16x16x32_bf16(qf[c], kf[j], sa[j], 0, 0, 0);
    }

    const int kbase = kt * 64;
    float p_v[4][4];
    #pragma unroll
    for (int q = 0; q < 4; ++q) {
      int qrl = w16 + g * 4 + q;                 // local row 0..127
      int qrow = qtb + qrl;                      // global row
      float mx = -1e30f;
      #pragma unroll
      for (int j = 0; j < 4; ++j) {
        float s = sa[j][q] * 0.125f;
        if (kbase + r16 + j * 16 > qrow) s = -1e30f;   // causal mask (elementwise)
        p_v[j][q] = s;
        mx = fmaxf(mx, s);
      }
      #pragma unroll
      for (int o = 1; o < 16; o <<= 1) mx = fmaxf(mx, __shfl_xor(mx, o));
      float mnew = fmaxf(m_r[q], mx);
      float ps = 0.f;
      #pragma unroll
      for (int j = 0; j < 4; ++j) {
        float p = __expf(p_v[j][q] - mnew);
        p_v[j][q] = p;
        ps += p;
      }
      #pragma unroll
      for (int o = 1; o < 16; o <<= 1) ps += __shfl_xor(ps, o);
      float alpha = __expf(m_r[q] - mnew);
      m_r[q] = mnew;
      l_r[q] = l_r[q] * alpha + ps;
      #pragma unroll
      for (int j = 0; j < 4; ++j) yacc[j][q] *= alpha;
      #pragma unroll
      for (int j = 0; j < 4; ++j) {
        int col = r16 + j * 16;
        Ps[qrl * 64 + (col ^ ((qrl & 7) << 3))] = (bf16)p_v[j][q];   // wave-private rows
      }
    }

    #pragma unroll
    for (int ks = 0; ks < 2; ++ks) {
      int prow = w16 + r16;
      bf16x8 pa = *reinterpret_cast<const bf16x8*>(&Ps[prow * 64 + (((g + 4 * ks) ^ (prow & 7)) * 8)]);
      #pragma unroll
      for (int j = 0; j < 4; ++j) {
        int vrow = j * 16 + r16;
        bf16x8 vb = *reinterpret_cast<const bf16x8*>(&Vs[vrow * 64 + (((g + 4 * ks) ^ (vrow & 7)) * 8)]);
        yacc[j] = __builtin_amdgcn_mfma_f32_16x16x32_bf16(pa, vb, yacc[j], 0, 0, 0);
      }
    }
  }

  #pragma unroll
  for (int q = 0; q < 4; ++q) {
    float inv = 1.0f / l_r[q];
    int tok = b * TDIM + qtb + w16 + g * 4 + q;
    #pragma unroll
    for (int j = 0; j < 4; ++j)
      y[(size_t)tok * CDIM + h * 64 + r16 + j * 16] = (bf16)(yacc[j][q] * inv);
  }
}

// ---------------- launcher ----------------
extern "C" void kernel_launch(void* const* d_in, const int* in_sizes, int n_in,
                              void* d_out, int out_size, void* d_ws, size_t ws_size,
                              hipStream_t stream) {
  (void)in_sizes; (void)n_in; (void)out_size;
  const int*   idx    = (const int*)  d_in[0];
  const float* wte    = (const float*)d_in[1];
  const float* wpe    = (const float*)d_in[2];
  const float* ln1_s  = (const float*)d_in[3];
  const float* ln1_b  = (const float*)d_in[4];
  const float* qkv_w  = (const float*)d_in[5];
  const float* qkv_b  = (const float*)d_in[6];
  const float* proj_w = (const float*)d_in[7];
  const float* proj_b = (const float*)d_in[8];
  const float* ln2_s  = (const float*)d_in[9];
  const float* ln2_b  = (const float*)d_in[10];
  const float* fc_w   = (const float*)d_in[11];
  const float* fc_b   = (const float*)d_in[12];
  const float* fcp_w  = (const float*)d_in[13];
  const float* fcp_b  = (const float*)d_in[14];
  const float* lnf_s  = (const float*)d_in[15];
  const float* lnf_b  = (const float*)d_in[16];
  float* logits = (float*)d_out;

  char* base = (char*)d_ws;
  size_t off = 0;
  auto alloc = [&](size_t bytes) -> void* {
    void* p = base + off;
    off += (bytes + 255) & ~(size_t)255;
    return p;
  };
  bf16*  wte_bf  = (bf16*) alloc((size_t)VDIM * CDIM * 2);   // keep FIRST (logits B-tail overreads land in ws)
  bf16*  wq_all  = (bf16*) alloc((size_t)LNUM * 3 * CDIM * CDIM * 2);
  bf16*  wp_all  = (bf16*) alloc((size_t)LNUM * CDIM * CDIM * 2);
  bf16*  wf_all  = (bf16*) alloc((size_t)LNUM * 4 * CDIM * CDIM * 2);
  bf16*  wfp_all = (bf16*) alloc((size_t)LNUM * 4 * CDIM * CDIM * 2);
  float* x       = (float*)alloc((size_t)NTOK * CDIM * 4);
  bf16*  hb      = (bf16*) alloc((size_t)NTOK * CDIM * 2);
  bf16*  qkv_bf  = (bf16*) alloc((size_t)NTOK * 3 * CDIM * 2);
  bf16*  vt      = (bf16*) alloc((size_t)BDIM * HNUM * 64 * TDIM * 2);
  bf16*  yb      = (bf16*) alloc((size_t)NTOK * CDIM * 2);
  bf16*  gb      = (bf16*) alloc((size_t)NTOK * 4 * CDIM * 2);
  if (off > ws_size) return;

  k_cvt_bf16<<<4096, 256, 0, stream>>>(wte, wte_bf, (long)VDIM * CDIM);
  k_trans_all<<<LNUM * TILES_LAYER, 256, 0, stream>>>(qkv_w, proj_w, fc_w, fcp_w,
                                                      wq_all, wp_all, wf_all, wfp_all);
  k_embed<<<NTOK, 256, 0, stream>>>(idx, wte, wpe, x);

  for (int l = 0; l < LNUM; ++l) {
    const bf16* wq  = wq_all  + (size_t)l * 3 * CDIM * CDIM;
    const bf16* wp  = wp_all  + (size_t)l * CDIM * CDIM;
    const bf16* wf  = wf_all  + (size_t)l * 4 * CDIM * CDIM;
    const bf16* wfp = wfp_all + (size_t)l * 4 * CDIM * CDIM;

    k_layernorm<<<NTOK, 256, 0, stream>>>(x, ln1_s + l*CDIM, ln1_b + l*CDIM, hb);
    k_gemm8<128,4><<<32 * 9, 512, 0, stream>>>(hb, wq, qkv_b + (size_t)l*3*CDIM, nullptr, qkv_bf, 3*CDIM, CDIM);
    k_vtrans<<<dim3(BDIM*HNUM, TDIM/64), 256, 0, stream>>>(qkv_bf, vt);
    k_attn<<<dim3(BDIM*HNUM, TDIM/128), 512, 0, stream>>>(qkv_bf, vt, yb);
    k_gemmp<<<32 * 6, 256, 0, stream>>>(yb, wp, proj_b + (size_t)l*CDIM, x, CDIM, CDIM);
    k_layernorm<<<NTOK, 256, 0, stream>>>(x, ln2_s + l*CDIM, ln2_b + l*CDIM, hb);
    k_gemm8<128,3><<<32 * 12, 512, 0, stream>>>(hb, wf, fc_b + (size_t)l*4*CDIM, nullptr, gb, 4*CDIM, CDIM);
    k_gemmp<<<32 * 6, 256, 0, stream>>>(gb, wfp, fcp_b + (size_t)l*CDIM, x, CDIM, 4*CDIM);
  }

  k_layernorm<<<NTOK, 256, 0, stream>>>(x, lnf_s, lnf_b, hb);
  int ntile = (VDIM + 255) / 256;  // 197; tail masked in epilogue, staging overreads stay in ws
  k_gemm_logits<<<16 * ntile, 512, 0, stream>>>(hb, wte_bf, logits, VDIM, CDIM);
}

// Round 11
// 1866.776 us; speedup vs baseline: 1.0080x; 1.0080x over previous
//
#include <hip/hip_runtime.h>
#include <math.h>

#define LNUM 6
#define HNUM 12
#define CDIM 768
#define VDIM 50257
#define BDIM 4
#define TDIM 1024
#define NTOK 4096   // B*T

typedef __bf16 bf16;
typedef __bf16 bf16x8 __attribute__((ext_vector_type(8)));
typedef float  floatx4 __attribute__((ext_vector_type(4)));
typedef unsigned int u32;

// async global->LDS, 16B per lane. LDS dest must be wave-uniform base; HW adds lane*16.
__device__ inline void gload16(const bf16* gsrc, bf16* lds) {
  __builtin_amdgcn_global_load_lds(
      (const __attribute__((address_space(1))) u32*)gsrc,
      (__attribute__((address_space(3))) u32*)lds, 16, 0, 0);
}

// ---------------- fp32 -> bf16 bulk convert (wte) ----------------
__global__ void k_cvt_bf16(const float* __restrict__ in, bf16* __restrict__ out, long n) {
  long i = ((long)blockIdx.x * blockDim.x + threadIdx.x) * 4;
  long stride = (long)gridDim.x * blockDim.x * 4;
  for (; i < n; i += stride) {
    float4 v = *reinterpret_cast<const float4*>(in + i);
    bf16 b0 = (bf16)v.x, b1 = (bf16)v.y, b2 = (bf16)v.z, b3 = (bf16)v.w;
    ushort4 pk;
    pk.x = __builtin_bit_cast(unsigned short, b0);
    pk.y = __builtin_bit_cast(unsigned short, b1);
    pk.z = __builtin_bit_cast(unsigned short, b2);
    pk.w = __builtin_bit_cast(unsigned short, b3);
    *reinterpret_cast<ushort4*>(out + i) = pk;
  }
}

// -------- batched transpose+convert for ALL layer weights (one launch) --------
#define TILES_QKV  1728
#define TILES_PROJ 576
#define TILES_FC   2304
#define TILES_FCP  2304
#define TILES_LAYER (TILES_QKV + TILES_PROJ + TILES_FC + TILES_FCP)

__global__ __launch_bounds__(256) void k_trans_all(
    const float* __restrict__ qkv_w, const float* __restrict__ proj_w,
    const float* __restrict__ fc_w, const float* __restrict__ fcp_w,
    bf16* __restrict__ wq, bf16* __restrict__ wp,
    bf16* __restrict__ wf, bf16* __restrict__ wfp) {
  __shared__ float tile[32][33];
  int bid = blockIdx.x;
  int layer = bid / TILES_LAYER, r = bid % TILES_LAYER;
  const float* src; bf16* dst; int K, N, tx, ty;
  if (r < TILES_QKV) {
    src = qkv_w + (size_t)layer * CDIM * 3 * CDIM; dst = wq + (size_t)layer * CDIM * 3 * CDIM;
    K = CDIM; N = 3 * CDIM; tx = r % 72; ty = r / 72;
  } else if (r < TILES_QKV + TILES_PROJ) {
    r -= TILES_QKV;
    src = proj_w + (size_t)layer * CDIM * CDIM; dst = wp + (size_t)layer * CDIM * CDIM;
    K = CDIM; N = CDIM; tx = r % 24; ty = r / 24;
  } else if (r < TILES_QKV + TILES_PROJ + TILES_FC) {
    r -= TILES_QKV + TILES_PROJ;
    src = fc_w + (size_t)layer * CDIM * 4 * CDIM; dst = wf + (size_t)layer * CDIM * 4 * CDIM;
    K = CDIM; N = 4 * CDIM; tx = r % 96; ty = r / 96;
  } else {
    r -= TILES_QKV + TILES_PROJ + TILES_FC;
    src = fcp_w + (size_t)layer * 4 * CDIM * CDIM; dst = wfp + (size_t)layer * 4 * CDIM * CDIM;
    K = 4 * CDIM; N = CDIM; tx = r % 24; ty = r / 24;
  }
  int n0 = tx * 32, k0 = ty * 32;
  int nx = threadIdx.x & 31, tyy = threadIdx.x >> 5;
  #pragma unroll
  for (int p = 0; p < 4; ++p) {
    int k = tyy + p * 8;
    tile[k][nx] = src[(size_t)(k0 + k) * N + n0 + nx];
  }
  __syncthreads();
  #pragma unroll
  for (int p = 0; p < 4; ++p) {
    int n = tyy + p * 8;
    dst[(size_t)(n0 + n) * K + k0 + nx] = (bf16)tile[nx][n];
  }
}

// ---------------- embedding ----------------
__global__ void k_embed(const int* __restrict__ idx, const float* __restrict__ wte,
                        const float* __restrict__ wpe, float* __restrict__ x) {
  int tok = blockIdx.x;
  int t = tok & (TDIM - 1);
  int id = idx[tok];
  const float* a = wte + (size_t)id * CDIM;
  const float* p = wpe + (size_t)t * CDIM;
  float* o = x + (size_t)tok * CDIM;
  for (int c = threadIdx.x; c < CDIM; c += 256) o[c] = a[c] + p[c];
}

// ---------------- layernorm: fp32 in -> bf16 out ----------------
__global__ __launch_bounds__(256) void k_layernorm(const float* __restrict__ x,
    const float* __restrict__ sc, const float* __restrict__ bi, bf16* __restrict__ out) {
  __shared__ float red[8];
  int row = blockIdx.x;
  const float* xr = x + (size_t)row * CDIM;
  int t = threadIdx.x;
  float v0 = xr[t], v1 = xr[t + 256], v2 = xr[t + 512];
  float s = v0 + v1 + v2;
  #pragma unroll
  for (int o = 32; o > 0; o >>= 1) s += __shfl_down(s, o);
  if ((t & 63) == 0) red[t >> 6] = s;
  __syncthreads();
  float mean = (red[0] + red[1] + red[2] + red[3]) * (1.0f / CDIM);
  float d0 = v0 - mean, d1 = v1 - mean, d2 = v2 - mean;
  float q = d0 * d0 + d1 * d1 + d2 * d2;
  #pragma unroll
  for (int o = 32; o > 0; o >>= 1) q += __shfl_down(q, o);
  if ((t & 63) == 0) red[4 + (t >> 6)] = q;
  __syncthreads();
  float var = (red[4] + red[5] + red[6] + red[7]) * (1.0f / CDIM);
  float rs = rsqrtf(var + 1e-5f);
  bf16* orow = out + (size_t)row * CDIM;
  orow[t]       = (bf16)(d0 * rs * sc[t]       + bi[t]);
  orow[t + 256] = (bf16)(d1 * rs * sc[t + 256] + bi[t + 256]);
  orow[t + 512] = (bf16)(d2 * rs * sc[t + 512] + bi[t + 512]);
}

__device__ inline float gelu_f(float x) {
  float x3 = x * x * x;
  return 0.5f * x * (1.0f + tanhf(0.7978845608028654f * (x + 0.044715f * x3)));
}

// ================= 128x128 BK=32 4-wave logits GEMM (3 blocks/CU) =================
// C[4096,N] = A[4096,K] * Bt[N,K]^T, f32 out, N-tail guarded.
// acc[4][4] = 64 AGPR/wave -> ~144 regs total -> 3 waves/SIMD -> 3 blocks/CU:
// co-resident blocks hide barrier drains + epilogue write bursts (vs 1 blk/CU at 224 regs).
// Schedule: proven k_gemmp skeleton — ph0{read B[p],A[p].lo | stage A(t+1)} ph1{read
// A[p].hi | stage B(t+2) | vmcnt(2)}. T2 swizzle pair. LDS 32KB.
__global__ __launch_bounds__(256, 3) void k_gemm_logits(
    const bf16* __restrict__ A, const bf16* __restrict__ Bt,
    float* __restrict__ Cf, int N, int K) {
  __shared__ __align__(16) bf16 smem[4 * 4096];
  bf16* Bs = smem;            // [2][4096]
  bf16* As = smem + 2 * 4096; // [2][4096]
  const int nwg = gridDim.x;  // 12576, %8==0
  const int id = blockIdx.x;
  const int swz = (id & 7) * (nwg >> 3) + (id >> 3);   // XCD-chunked
  const int m0 = (swz & 31) * 128;
  const int n0 = (swz >> 5) * 128;
  const int tid = threadIdx.x, lane = tid & 63, wave = tid >> 6;
  const int wr = wave >> 1, wc = wave & 1;   // 2M x 2N
  const int g = lane >> 4, r16 = lane & 15;
  const int numK = K >> 5;
  const int wsl = wave * 512;

  const int srow = wave * 16 + (lane >> 2);            // rows 0..63
  const int scol = ((lane & 3) ^ ((lane >> 3) & 3)) * 8;   // T2 source permute
  const bf16* at  = A  + (size_t)(m0 + srow) * K + scol;
  const bf16* at1 = A  + (size_t)(m0 + srow + 64) * K + scol;
  const bf16* bt  = Bt + (size_t)(n0 + srow) * K + scol;
  const bf16* bt1 = Bt + (size_t)(n0 + srow + 64) * K + scol;
  const int sw = (g ^ ((r16 >> 1) & 3)) * 8;               // T2 read XOR
  const int a_off = (wr * 64 + r16) * 32 + sw;
  const int b_off = (wc * 64 + r16) * 32 + sw;

  floatx4 acc[4][4] = {};

#define STBL(s0, s1, pb) do { gload16((s0), Bs + (pb) * 4096 + wsl); \
                              gload16((s1), Bs + (pb) * 4096 + 2048 + wsl); } while (0)
#define STAL(s0, s1, pb) do { gload16((s0), As + (pb) * 4096 + wsl); \
                              gload16((s1), As + (pb) * 4096 + 2048 + wsl); } while (0)

  STBL(bt, bt1, 0);
  STAL(at, at1, 0);
  STBL(bt + 32, bt1 + 32, 1);
  asm volatile("s_waitcnt vmcnt(2)" ::: "memory");
  __builtin_amdgcn_s_barrier();

  for (int t = 0; t < numK; ++t) {
    const int p = t & 1, pn = p ^ 1;
    bf16x8 af[2], bfr[4];

    // ---- phase 0: mgroup 0 ----
    #pragma unroll
    for (int j = 0; j < 4; ++j) bfr[j] = *(const bf16x8*)&Bs[p * 4096 + b_off + j * 512];
    #pragma unroll
    for (int i = 0; i < 2; ++i) af[i] = *(const bf16x8*)&As[p * 4096 + a_off + i * 512];
    if (t + 1 < numK) STAL(at + 32, at1 + 32, pn);
    __builtin_amdgcn_s_barrier();
    asm volatile("s_waitcnt lgkmcnt(0)" ::: "memory");
    __builtin_amdgcn_s_setprio(1);
    #pragma unroll
    for (int i = 0; i < 2; ++i)
      #pragma unroll
      for (int j = 0; j < 4; ++j)
        acc[i][j] = __builtin_amdgcn_mfma_f32_16x16x32_bf16(af[i], bfr[j], acc[i][j], 0, 0, 0);
    __builtin_amdgcn_s_setprio(0);
    __builtin_amdgcn_s_barrier();

    // ---- phase 1: mgroup 1 (B regs reused) ----
    #pragma unroll
    for (int i = 0; i < 2; ++i) af[i] = *(const bf16x8*)&As[p * 4096 + a_off + (i + 2) * 512];
    if (t + 2 < numK) STBL(bt + 64, bt1 + 64, p);
    __builtin_amdgcn_s_barrier();
    asm volatile("s_waitcnt lgkmcnt(0)" ::: "memory");
    __builtin_amdgcn_s_setprio(1);
    #pragma unroll
    for (int i = 0; i < 2; ++i)
      #pragma unroll
      for (int j = 0; j < 4; ++j)
        acc[i + 2][j] = __builtin_amdgcn_mfma_f32_16x16x32_bf16(af[i], bfr[j], acc[i + 2][j], 0, 0, 0);
    __builtin_amdgcn_s_setprio(0);
    if (t + 2 < numK) { asm volatile("s_waitcnt vmcnt(2)" ::: "memory"); }
    else              { asm volatile("s_waitcnt vmcnt(0)" ::: "memory"); }
    __builtin_amdgcn_s_barrier();

    at += 32; at1 += 32; bt += 32; bt1 += 32;
  }
#undef STBL
#undef STAL

  // epilogue: wave-private LDS transpose (f32, stride 68) -> contiguous 16B stores
  float* sb = reinterpret_cast<float*>(smem) + wave * 1088;  // 16 rows x 68
  const int seg = lane & 15, rq = lane >> 4;
  const int mrow_base = m0 + wr * 64;
  const int ncol_base = n0 + wc * 64;
  #pragma unroll
  for (int mf = 0; mf < 4; ++mf) {
    #pragma unroll
    for (int nf = 0; nf < 4; ++nf) {
      #pragma unroll
      for (int q = 0; q < 4; ++q)
        sb[(g * 4 + q) * 68 + nf * 16 + r16] = acc[mf][nf][q];
    }
    #pragma unroll
    for (int pz = 0; pz < 4; ++pz) {
      int row = rq + pz * 4;
      floatx4 v = *reinterpret_cast<const floatx4*>(&sb[row * 68 + seg * 4]);
      int m = mrow_base + mf * 16 + row;
      int n = ncol_base + seg * 4;
      if (n + 4 <= N) {
        __builtin_memcpy(&Cf[(size_t)m * N + n], &v, 16);
      } else {
        #pragma unroll
        for (int e = 0; e < 4; ++e)
          if (n + e < N) Cf[(size_t)m * N + n + e] = v[e];
      }
    }
  }
}

// ================= TBMx256 BK=32 pipelined MFMA GEMM (qkv / fc) =================
template<int TBM, int EPI>   // EPI: 3 +bias+gelu ->bf16, 4 +bias ->bf16
__global__ __launch_bounds__(512, 1) void k_gemm8(
    const bf16* __restrict__ A, const bf16* __restrict__ Bt,
    const float* __restrict__ bias,
    float* __restrict__ Cf, bf16* __restrict__ Cb,
    int N, int K) {
  constexpr int MI = TBM / 32;
  constexpr int MH = MI / 2;
  constexpr int MTILES = 4096 / TBM;
  __shared__ __align__(16) bf16 smem[2 * 8192 + 2 * TBM * 32];
  bf16* Bs = smem;
  bf16* As = smem + 2 * 8192;
  const int nwg = gridDim.x;
  const int id = blockIdx.x;
  const int swz = (id & 7) * (nwg >> 3) + (id >> 3);
  const int m0 = (swz % MTILES) * TBM;
  const int n0 = (swz / MTILES) * 256;
  const int tid = threadIdx.x, lane = tid & 63, wave = tid >> 6;
  const int wr = wave >> 2, wc = wave & 3;
  const int g = lane >> 4, r16 = lane & 15;
  const int numK = K >> 5;
  const int wsl = wave * 512;

  const int srow = wave * 16 + (lane >> 2);
  const int scol = ((lane & 3) ^ ((lane >> 3) & 3)) * 8;
  const bf16* at  = A  + (size_t)(m0 + srow) * K + scol;
  const bf16* at1 = A  + (size_t)(m0 + srow + 128) * K + scol;
  const bf16* bt  = Bt + (size_t)(n0 + srow) * K + scol;
  const bf16* bt1 = Bt + (size_t)(n0 + srow + 128) * K + scol;
  const int sw = (g ^ ((r16 >> 1) & 3)) * 8;
  const int a_off = (wr * (TBM / 2) + r16) * 32 + sw;
  const int b_off = (wc * 64 + r16) * 32 + sw;

  floatx4 acc[MI][4] = {};

#define STB(s0, s1, pb) do { gload16((s0), Bs + (pb) * 8192 + wsl); \
                             gload16((s1), Bs + (pb) * 8192 + wsl + 4096); } while (0)
#define STA(s0, s1, pb) do { gload16((s0), As + (pb) * TBM * 32 + wsl); \
                             if constexpr (TBM == 256) gload16((s1), As + (pb) * TBM * 32 + wsl + 4096); } while (0)

  STB(bt, bt1, 0);
  STA(at, at1, 0);
  STB(bt + 32, bt1 + 32, 1);
  asm volatile("s_waitcnt vmcnt(2)" ::: "memory");
  __builtin_amdgcn_s_barrier();

  for (int t = 0; t < numK; ++t) {
    const int p = t & 1, pn = p ^ 1;
    bf16x8 af[MH], bfr[4];

    #pragma unroll
    for (int j = 0; j < 4; ++j) bfr[j] = *(const bf16x8*)&Bs[p * 8192 + b_off + j * 512];
    #pragma unroll
    for (int i = 0; i < MH; ++i) af[i] = *(const bf16x8*)&As[p * TBM * 32 + a_off + i * 512];
    if (t + 1 < numK) STA(at + 32, at1 + 32, pn);
    __builtin_amdgcn_s_barrier();
    asm volatile("s_waitcnt lgkmcnt(0)" ::: "memory");
    __builtin_amdgcn_s_setprio(1);
    #pragma unroll
    for (int i = 0; i < MH; ++i)
      #pragma unroll
      for (int j = 0; j < 4; ++j)
        acc[i][j] = __builtin_amdgcn_mfma_f32_16x16x32_bf16(af[i], bfr[j], acc[i][j], 0, 0, 0);
    __builtin_amdgcn_s_setprio(0);
    __builtin_amdgcn_s_barrier();

    #pragma unroll
    for (int i = 0; i < MH; ++i) af[i] = *(const bf16x8*)&As[p * TBM * 32 + a_off + (i + MH) * 512];
    if (t + 2 < numK) STB(bt + 64, bt1 + 64, p);
    __builtin_amdgcn_s_barrier();
    asm volatile("s_waitcnt lgkmcnt(0)" ::: "memory");
    __builtin_amdgcn_s_setprio(1);
    #pragma unroll
    for (int i = 0; i < MH; ++i)
      #pragma unroll
      for (int j = 0; j < 4; ++j)
        acc[i + MH][j] = __builtin_amdgcn_mfma_f32_16x16x32_bf16(af[i], bfr[j], acc[i + MH][j], 0, 0, 0);
    __builtin_amdgcn_s_setprio(0);
    if (t + 2 < numK) { asm volatile("s_waitcnt vmcnt(2)" ::: "memory"); }
    else              { asm volatile("s_waitcnt vmcnt(0)" ::: "memory"); }
    __builtin_amdgcn_s_barrier();

    at += 32; at1 += 32; bt += 32; bt1 += 32;
  }
#undef STB
#undef STA

  bf16* sb = smem + wave * 1152;
  const int rr_rd = lane & 15, seg = lane >> 4;
  const int nb = n0 + wc * 64 + r16;
  float bv[4];
  #pragma unroll
  for (int j = 0; j < 4; ++j) bv[j] = bias[nb + j * 16];
  #pragma unroll
  for (int mf = 0; mf < MI; ++mf) {
    #pragma unroll
    for (int j = 0; j < 4; ++j) {
      #pragma unroll
      for (int q = 0; q < 4; ++q) {
        float v = acc[mf][j][q] + bv[j];
        if (EPI == 3) v = gelu_f(v);
        sb[(g * 4 + q) * 72 + j * 16 + r16] = (bf16)v;
      }
    }
    bf16x8 o0 = *(const bf16x8*)&sb[rr_rd * 72 + seg * 16];
    bf16x8 o1 = *(const bf16x8*)&sb[rr_rd * 72 + seg * 16 + 8];
    size_t orow = (size_t)(m0 + wr * (TBM / 2) + mf * 16 + rr_rd) * N + (n0 + wc * 64 + seg * 16);
    *(bf16x8*)&Cb[orow] = o0;
    *(bf16x8*)&Cb[orow + 8] = o1;
  }
}

// ---------------- legacy 2-phase NT GEMM (proj / fcp: N=768) ----------------
template<int TBM, int MI, int NI, int EPI>
__global__ __launch_bounds__(256) void k_gemm(
    const bf16* __restrict__ A, const bf16* __restrict__ Bt,
    const float* __restrict__ bias, const float* __restrict__ resid,
    float* __restrict__ Cf, bf16* __restrict__ Cb,
    int M, int N, int K) {
  constexpr int BN = 128;
  constexpr int WGN = BN / (NI * 16);
  constexpr int AI = TBM / 32;
  constexpr int BI = BN / 32;
  __shared__ __align__(16) bf16 As[TBM * 64];
  __shared__ __align__(16) bf16 Bs[BN * 64];
  const int m0 = blockIdx.x * TBM, n0 = blockIdx.y * BN;
  const int tid = threadIdx.x;
  const int lane = tid & 63, wave = tid >> 6;
  const int wr = wave / WGN, wc = wave % WGN;
  const int l8 = lane >> 3, s8 = lane & 7;
  const int g = lane >> 4, r16 = lane & 15;

  floatx4 acc[MI][NI] = {};

  const bf16* a_src = A + (size_t)(m0 + l8) * K + s8 * 8;
  const bf16* b_src = Bt + (size_t)(n0 + l8) * K + s8 * 8;

  for (int k0 = 0; k0 < K; k0 += 64) {
    #pragma unroll
    for (int t = 0; t < AI; ++t) {
      int row0 = wave * (TBM / 4) + t * 8;
      gload16(a_src + (size_t)row0 * K + k0, &As[row0 * 64]);
    }
    #pragma unroll
    for (int t = 0; t < BI; ++t) {
      int row0 = wave * 32 + t * 8;
      gload16(b_src + (size_t)row0 * K + k0, &Bs[row0 * 64]);
    }
    __syncthreads();
    #pragma unroll
    for (int kk = 0; kk < 2; ++kk) {
      bf16x8 af[MI], bfr[NI];
      #pragma unroll
      for (int i = 0; i < MI; ++i)
        af[i] = *reinterpret_cast<const bf16x8*>(&As[(wr * MI * 16 + i * 16 + r16) * 64 + g * 8 + kk * 32]);
      #pragma unroll
      for (int j = 0; j < NI; ++j)
        bfr[j] = *reinterpret_cast<const bf16x8*>(&Bs[(wc * NI * 16 + j * 16 + r16) * 64 + g * 8 + kk * 32]);
      #pragma unroll
      for (int i = 0; i < MI; ++i) {
        #pragma unroll
        for (int j = 0; j < NI; ++j)
          acc[i][j] = __builtin_amdgcn_mfma_f32_16x16x32_bf16(af[i], bfr[j], acc[i][j], 0, 0, 0);
      }
    }
    __syncthreads();
  }

  int mb = m0 + wr * MI * 16 + g * 4;
  int nb = n0 + wc * NI * 16 + r16;
  #pragma unroll
  for (int j = 0; j < NI; ++j) {
    int n = nb + j * 16;
    if (n >= N) continue;
    float bv = (EPI >= 2) ? bias[n] : 0.0f;
    #pragma unroll
    for (int i = 0; i < MI; ++i) {
      #pragma unroll
      for (int q = 0; q < 4; ++q) {
        int m = mb + i * 16 + q;
        float v = acc[i][j][q] + bv;
        size_t o = (size_t)m * N + n;
        if (EPI == 2)      Cf[o] = v + resid[o];
        else if (EPI == 3) Cb[o] = (bf16)gelu_f(v);
        else if (EPI == 4) Cb[o] = (bf16)v;
        else               Cf[o] = v;
      }
    }
  }
}

// ---------------- V transpose: qkv_bf V-part -> vt[bh][d][t] bf16 ----------------
__global__ __launch_bounds__(256) void k_vtrans(const bf16* __restrict__ qkv, bf16* __restrict__ vt) {
  __shared__ bf16 tile[64][72];
  int bh = blockIdx.x, t0 = blockIdx.y * 64;
  int b = bh / HNUM, h = bh % HNUM;
  int tid = threadIdx.x;
  int r8 = tid >> 3, s8 = tid & 7;
  #pragma unroll
  for (int p = 0; p < 2; ++p) {
    int row = p * 32 + r8;
    uint4 v = *reinterpret_cast<const uint4*>(
        qkv + (size_t)(b * TDIM + t0 + row) * (3 * CDIM) + 2 * CDIM + h * 64 + s8 * 8);
    *reinterpret_cast<uint4*>(&tile[row][s8 * 8]) = v;
  }
  __syncthreads();
  int d = tid >> 2, q4 = tid & 3;
  #pragma unroll
  for (int half = 0; half < 2; ++half) {
    int t = q4 * 16 + half * 8;
    bf16x8 o;
    #pragma unroll
    for (int u = 0; u < 8; ++u) o[u] = tile[t + u][d];
    *reinterpret_cast<bf16x8*>(vt + (size_t)bh * (64 * TDIM) + (size_t)d * TDIM + t0 + t) = o;
  }
}

// ---------------- MFMA flash attention (QBLK=64, 4 waves — r8 proven) ----------------
__global__ __launch_bounds__(256) void k_attn(const bf16* __restrict__ qkv,
                                              const bf16* __restrict__ vt,
                                              bf16* __restrict__ y) {
  __shared__ __align__(16) bf16 Ks[64 * 64];
  __shared__ __align__(16) bf16 Vs[64 * 64];
  __shared__ __align__(16) bf16 Ps[64 * 64];
  const int bh = blockIdx.x, qt = blockIdx.y;
  const int b = bh / HNUM, h = bh % HNUM;
  const int tid = threadIdx.x, lane = tid & 63, wave = tid >> 6;
  const int g = lane >> 4, r16 = lane & 15;
  const int w16 = wave * 16;
  const int r8 = tid >> 3, s8 = tid & 7;

  bf16x8 qf[2];
  {
    const bf16* qsrc = qkv + (size_t)(b * TDIM + qt * 64 + w16 + r16) * (3 * CDIM) + h * 64 + g * 8;
    qf[0] = *reinterpret_cast<const bf16x8*>(qsrc);
    qf[1] = *reinterpret_cast<const bf16x8*>(qsrc + 32);
  }

  float m_r[4], l_r[4];
  floatx4 yacc[4] = {};
  #pragma unroll
  for (int q = 0; q < 4; ++q) { m_r[q] = -1e30f; l_r[q] = 0.f; }

  for (int kt = 0; kt <= qt; ++kt) {
    __syncthreads();
    #pragma unroll
    for (int p = 0; p < 2; ++p) {
      int row = p * 32 + r8;
      uint4 kv = *reinterpret_cast<const uint4*>(
          qkv + (size_t)(b * TDIM + kt * 64 + row) * (3 * CDIM) + CDIM + h * 64 + s8 * 8);
      *reinterpret_cast<uint4*>(&Ks[row * 64 + ((s8 ^ (row & 7)) * 8)]) = kv;
      uint4 vv = *reinterpret_cast<const uint4*>(
          vt + (size_t)bh * (64 * TDIM) + (size_t)row * TDIM + kt * 64 + s8 * 8);
      *reinterpret_cast<uint4*>(&Vs[row * 64 + ((s8 ^ (row & 7)) * 8)]) = vv;
    }
    __syncthreads();

    floatx4 sa[4] = {};
    #pragma unroll
    for (int c = 0; c < 2; ++c) {
      bf16x8 kf[4];
      #pragma unroll
      for (int j = 0; j < 4; ++j) {
        int krow = j * 16 + r16;
        kf[j] = *reinterpret_cast<const bf16x8*>(&Ks[krow * 64 + (((g + 4 * c) ^ (krow & 7)) * 8)]);
      }
      #pragma unroll
      for (int j = 0; j < 4; ++j)
        sa[j] = __builtin_amdgcn_mfma_f32_16x16x32_bf16(qf[c], kf[j], sa[j], 0, 0, 0);
    }

    const bool diag = (kt == qt);
    float p_v[4][4];
    #pragma unroll
    for (int q = 0; q < 4; ++q) {
      int qrow = w16 + g * 4 + q;
      float mx = -1e30f;
      #pragma unroll
      for (int j = 0; j < 4; ++j) {
        float s = sa[j][q] * 0.125f;
        if (diag && (r16 + j * 16) > qrow) s = -1e30f;
        p_v[j][q] = s;
        mx = fmaxf(mx, s);
      }
      #pragma unroll
      for (int o = 1; o < 16; o <<= 1) mx = fmaxf(mx, __shfl_xor(mx, o));
      float mnew = fmaxf(m_r[q], mx);
      float ps = 0.f;
      #pragma unroll
      for (int j = 0; j < 4; ++j) {
        float p = __expf(p_v[j][q] - mnew);
        p_v[j][q] = p;
        ps += p;
      }
      #pragma unroll
      for (int o = 1; o < 16; o <<= 1) ps += __shfl_xor(ps, o);
      float alpha = __expf(m_r[q] - mnew);
      m_r[q] = mnew;
      l_r[q] = l_r[q] * alpha + ps;
      #pragma unroll
      for (int j = 0; j < 4; ++j) yacc[j][q] *= alpha;
      #pragma unroll
      for (int j = 0; j < 4; ++j) {
        int col = r16 + j * 16;
        Ps[qrow * 64 + (col ^ ((qrow & 7) << 3))] = (bf16)p_v[j][q];
      }
    }

    #pragma unroll
    for (int ks = 0; ks < 2; ++ks) {
      int prow = w16 + r16;
      bf16x8 pa = *reinterpret_cast<const bf16x8*>(&Ps[prow * 64 + (((g + 4 * ks) ^ (prow & 7)) * 8)]);
      #pragma unroll
      for (int j = 0; j < 4; ++j) {
        int vrow = j * 16 + r16;
        bf16x8 vb = *reinterpret_cast<const bf16x8*>(&Vs[vrow * 64 + (((g + 4 * ks) ^ (vrow & 7)) * 8)]);
        yacc[j] = __builtin_amdgcn_mfma_f32_16x16x32_bf16(pa, vb, yacc[j], 0, 0, 0);
      }
    }
  }

  #pragma unroll
  for (int q = 0; q < 4; ++q) {
    float inv = 1.0f / l_r[q];
    int tok = b * TDIM + qt * 64 + w16 + g * 4 + q;
    #pragma unroll
    for (int j = 0; j < 4; ++j)
      y[(size_t)tok * CDIM + h * 64 + r16 + j * 16] = (bf16)(yacc[j][q] * inv);
  }
}

// ---------------- launcher ----------------
extern "C" void kernel_launch(void* const* d_in, const int* in_sizes, int n_in,
                              void* d_out, int out_size, void* d_ws, size_t ws_size,
                              hipStream_t stream) {
  (void)in_sizes; (void)n_in; (void)out_size;
  const int*   idx    = (const int*)  d_in[0];
  const float* wte    = (const float*)d_in[1];
  const float* wpe    = (const float*)d_in[2];
  const float* ln1_s  = (const float*)d_in[3];
  const float* ln1_b  = (const float*)d_in[4];
  const float* qkv_w  = (const float*)d_in[5];
  const float* qkv_b  = (const float*)d_in[6];
  const float* proj_w = (const float*)d_in[7];
  const float* proj_b = (const float*)d_in[8];
  const float* ln2_s  = (const float*)d_in[9];
  const float* ln2_b  = (const float*)d_in[10];
  const float* fc_w   = (const float*)d_in[11];
  const float* fc_b   = (const float*)d_in[12];
  const float* fcp_w  = (const float*)d_in[13];
  const float* fcp_b  = (const float*)d_in[14];
  const float* lnf_s  = (const float*)d_in[15];
  const float* lnf_b  = (const float*)d_in[16];
  float* logits = (float*)d_out;

  char* base = (char*)d_ws;
  size_t off = 0;
  auto alloc = [&](size_t bytes) -> void* {
    void* p = base + off;
    off += (bytes + 255) & ~(size_t)255;
    return p;
  };
  bf16*  wte_bf  = (bf16*) alloc((size_t)VDIM * CDIM * 2);   // keep FIRST (logits B-tail overreads land in ws)
  bf16*  wq_all  = (bf16*) alloc((size_t)LNUM * 3 * CDIM * CDIM * 2);
  bf16*  wp_all  = (bf16*) alloc((size_t)LNUM * CDIM * CDIM * 2);
  bf16*  wf_all  = (bf16*) alloc((size_t)LNUM * 4 * CDIM * CDIM * 2);
  bf16*  wfp_all = (bf16*) alloc((size_t)LNUM * 4 * CDIM * CDIM * 2);
  float* x       = (float*)alloc((size_t)NTOK * CDIM * 4);
  bf16*  hb      = (bf16*) alloc((size_t)NTOK * CDIM * 2);
  bf16*  qkv_bf  = (bf16*) alloc((size_t)NTOK * 3 * CDIM * 2);
  bf16*  vt      = (bf16*) alloc((size_t)BDIM * HNUM * 64 * TDIM * 2);
  bf16*  yb      = (bf16*) alloc((size_t)NTOK * CDIM * 2);
  bf16*  gb      = (bf16*) alloc((size_t)NTOK * 4 * CDIM * 2);
  if (off > ws_size) return;

  k_cvt_bf16<<<4096, 256, 0, stream>>>(wte, wte_bf, (long)VDIM * CDIM);
  k_trans_all<<<LNUM * TILES_LAYER, 256, 0, stream>>>(qkv_w, proj_w, fc_w, fcp_w,
                                                      wq_all, wp_all, wf_all, wfp_all);
  k_embed<<<NTOK, 256, 0, stream>>>(idx, wte, wpe, x);

  for (int l = 0; l < LNUM; ++l) {
    const bf16* wq  = wq_all  + (size_t)l * 3 * CDIM * CDIM;
    const bf16* wp  = wp_all  + (size_t)l * CDIM * CDIM;
    const bf16* wf  = wf_all  + (size_t)l * 4 * CDIM * CDIM;
    const bf16* wfp = wfp_all + (size_t)l * 4 * CDIM * CDIM;

    k_layernorm<<<NTOK, 256, 0, stream>>>(x, ln1_s + l*CDIM, ln1_b + l*CDIM, hb);
    k_gemm8<128,4><<<32 * 9, 512, 0, stream>>>(hb, wq, qkv_b + (size_t)l*3*CDIM, nullptr, qkv_bf, 3*CDIM, CDIM);
    k_vtrans<<<dim3(BDIM*HNUM, TDIM/64), 256, 0, stream>>>(qkv_bf, vt);
    k_attn<<<dim3(BDIM*HNUM, TDIM/64), 256, 0, stream>>>(qkv_bf, vt, yb);
    k_gemm<64,4,2,2><<<dim3(NTOK/64, 6), 256, 0, stream>>>(yb, wp, proj_b + (size_t)l*CDIM, x, x, nullptr, NTOK, CDIM, CDIM);
    k_layernorm<<<NTOK, 256, 0, stream>>>(x, ln2_s + l*CDIM, ln2_b + l*CDIM, hb);
    k_gemm8<128,3><<<32 * 12, 512, 0, stream>>>(hb, wf, fc_b + (size_t)l*4*CDIM, nullptr, gb, 4*CDIM, CDIM);
    k_gemm<64,4,2,2><<<dim3(NTOK/64, 6), 256, 0, stream>>>(gb, wfp, fcp_b + (size_t)l*CDIM, x, x, nullptr, NTOK, CDIM, 4*CDIM);
  }

  k_layernorm<<<NTOK, 256, 0, stream>>>(x, lnf_s, lnf_b, hb);
  int ntile = (VDIM + 127) / 128;  // 393 n-tiles; tail guarded, staging overreads stay in ws
  k_gemm_logits<<<32 * ntile, 256, 0, stream>>>(hb, wte_bf, logits, VDIM, CDIM);
}

// Round 12
// 1796.010 us; speedup vs baseline: 1.0477x; 1.0394x over previous
//
#include <hip/hip_runtime.h>
#include <math.h>

#define LNUM 6
#define HNUM 12
#define CDIM 768
#define VDIM 50257
#define BDIM 4
#define TDIM 1024
#define NTOK 4096   // B*T

typedef __bf16 bf16;
typedef __bf16 bf16x8 __attribute__((ext_vector_type(8)));
typedef float  floatx4 __attribute__((ext_vector_type(4)));
typedef unsigned int u32;

// async global->LDS, 16B per lane. LDS dest must be wave-uniform base; HW adds lane*16.
__device__ inline void gload16(const bf16* gsrc, bf16* lds) {
  __builtin_amdgcn_global_load_lds(
      (const __attribute__((address_space(1))) u32*)gsrc,
      (__attribute__((address_space(3))) u32*)lds, 16, 0, 0);
}

// ---------------- fp32 -> bf16 bulk convert (wte) ----------------
__global__ void k_cvt_bf16(const float* __restrict__ in, bf16* __restrict__ out, long n) {
  long i = ((long)blockIdx.x * blockDim.x + threadIdx.x) * 4;
  long stride = (long)gridDim.x * blockDim.x * 4;
  for (; i < n; i += stride) {
    float4 v = *reinterpret_cast<const float4*>(in + i);
    bf16 b0 = (bf16)v.x, b1 = (bf16)v.y, b2 = (bf16)v.z, b3 = (bf16)v.w;
    ushort4 pk;
    pk.x = __builtin_bit_cast(unsigned short, b0);
    pk.y = __builtin_bit_cast(unsigned short, b1);
    pk.z = __builtin_bit_cast(unsigned short, b2);
    pk.w = __builtin_bit_cast(unsigned short, b3);
    *reinterpret_cast<ushort4*>(out + i) = pk;
  }
}

// -------- batched transpose+convert for ALL layer weights (one launch) --------
#define TILES_QKV  1728
#define TILES_PROJ 576
#define TILES_FC   2304
#define TILES_FCP  2304
#define TILES_LAYER (TILES_QKV + TILES_PROJ + TILES_FC + TILES_FCP)

__global__ __launch_bounds__(256) void k_trans_all(
    const float* __restrict__ qkv_w, const float* __restrict__ proj_w,
    const float* __restrict__ fc_w, const float* __restrict__ fcp_w,
    bf16* __restrict__ wq, bf16* __restrict__ wp,
    bf16* __restrict__ wf, bf16* __restrict__ wfp) {
  __shared__ float tile[32][33];
  int bid = blockIdx.x;
  int layer = bid / TILES_LAYER, r = bid % TILES_LAYER;
  const float* src; bf16* dst; int K, N, tx, ty;
  if (r < TILES_QKV) {
    src = qkv_w + (size_t)layer * CDIM * 3 * CDIM; dst = wq + (size_t)layer * CDIM * 3 * CDIM;
    K = CDIM; N = 3 * CDIM; tx = r % 72; ty = r / 72;
  } else if (r < TILES_QKV + TILES_PROJ) {
    r -= TILES_QKV;
    src = proj_w + (size_t)layer * CDIM * CDIM; dst = wp + (size_t)layer * CDIM * CDIM;
    K = CDIM; N = CDIM; tx = r % 24; ty = r / 24;
  } else if (r < TILES_QKV + TILES_PROJ + TILES_FC) {
    r -= TILES_QKV + TILES_PROJ;
    src = fc_w + (size_t)layer * CDIM * 4 * CDIM; dst = wf + (size_t)layer * CDIM * 4 * CDIM;
    K = CDIM; N = 4 * CDIM; tx = r % 96; ty = r / 96;
  } else {
    r -= TILES_QKV + TILES_PROJ + TILES_FC;
    src = fcp_w + (size_t)layer * 4 * CDIM * CDIM; dst = wfp + (size_t)layer * 4 * CDIM * CDIM;
    K = 4 * CDIM; N = CDIM; tx = r % 24; ty = r / 24;
  }
  int n0 = tx * 32, k0 = ty * 32;
  int nx = threadIdx.x & 31, tyy = threadIdx.x >> 5;
  #pragma unroll
  for (int p = 0; p < 4; ++p) {
    int k = tyy + p * 8;
    tile[k][nx] = src[(size_t)(k0 + k) * N + n0 + nx];
  }
  __syncthreads();
  #pragma unroll
  for (int p = 0; p < 4; ++p) {
    int n = tyy + p * 8;
    dst[(size_t)(n0 + n) * K + k0 + nx] = (bf16)tile[nx][n];
  }
}

// ---------------- embedding ----------------
__global__ void k_embed(const int* __restrict__ idx, const float* __restrict__ wte,
                        const float* __restrict__ wpe, float* __restrict__ x) {
  int tok = blockIdx.x;
  int t = tok & (TDIM - 1);
  int id = idx[tok];
  const float* a = wte + (size_t)id * CDIM;
  const float* p = wpe + (size_t)t * CDIM;
  float* o = x + (size_t)tok * CDIM;
  for (int c = threadIdx.x; c < CDIM; c += 256) o[c] = a[c] + p[c];
}

// ---------------- layernorm: fp32 in -> bf16 out ----------------
__global__ __launch_bounds__(256) void k_layernorm(const float* __restrict__ x,
    const float* __restrict__ sc, const float* __restrict__ bi, bf16* __restrict__ out) {
  __shared__ float red[8];
  int row = blockIdx.x;
  const float* xr = x + (size_t)row * CDIM;
  int t = threadIdx.x;
  float v0 = xr[t], v1 = xr[t + 256], v2 = xr[t + 512];
  float s = v0 + v1 + v2;
  #pragma unroll
  for (int o = 32; o > 0; o >>= 1) s += __shfl_down(s, o);
  if ((t & 63) == 0) red[t >> 6] = s;
  __syncthreads();
  float mean = (red[0] + red[1] + red[2] + red[3]) * (1.0f / CDIM);
  float d0 = v0 - mean, d1 = v1 - mean, d2 = v2 - mean;
  float q = d0 * d0 + d1 * d1 + d2 * d2;
  #pragma unroll
  for (int o = 32; o > 0; o >>= 1) q += __shfl_down(q, o);
  if ((t & 63) == 0) red[4 + (t >> 6)] = q;
  __syncthreads();
  float var = (red[4] + red[5] + red[6] + red[7]) * (1.0f / CDIM);
  float rs = rsqrtf(var + 1e-5f);
  bf16* orow = out + (size_t)row * CDIM;
  orow[t]       = (bf16)(d0 * rs * sc[t]       + bi[t]);
  orow[t + 256] = (bf16)(d1 * rs * sc[t + 256] + bi[t + 256]);
  orow[t + 512] = (bf16)(d2 * rs * sc[t + 512] + bi[t + 512]);
}

__device__ inline float gelu_f(float x) {
  float x3 = x * x * x;
  return 0.5f * x * (1.0f + tanhf(0.7978845608028654f * (x + 0.044715f * x3)));
}

// ================= 256x256 BK=32 logits GEMM (r8-proven config) =================
// 8 waves, A/B 2-buf, vmcnt(2), T2 swizzle pair, f32 LDS-transpose epilogue.
__global__ __launch_bounds__(512, 1) void k_gemm_logits(
    const bf16* __restrict__ A, const bf16* __restrict__ Bt,
    float* __restrict__ Cf, int N, int K) {
  __shared__ __align__(16) bf16 smem[4 * 8192];
  bf16* Bs = smem;             // [2][8192]
  bf16* As = smem + 2 * 8192;  // [2][8192]
  const int nwg = gridDim.x;   // 3152, %8==0
  const int id = blockIdx.x;
  const int swz = (id & 7) * (nwg >> 3) + (id >> 3);
  const int m0 = (swz & 15) * 256;
  const int n0 = (swz >> 4) * 256;
  const int tid = threadIdx.x, lane = tid & 63, wave = tid >> 6;
  const int wr = wave >> 2, wc = wave & 3;
  const int g = lane >> 4, r16 = lane & 15;
  const int numK = K >> 5;
  const int wsl = wave * 512;

  const int srow = wave * 16 + (lane >> 2);
  const int scol = ((lane & 3) ^ ((lane >> 3) & 3)) * 8;   // T2 source permute
  const bf16* at  = A  + (size_t)(m0 + srow) * K + scol;
  const bf16* at1 = A  + (size_t)(m0 + srow + 128) * K + scol;
  const bf16* bt  = Bt + (size_t)(n0 + srow) * K + scol;
  const bf16* bt1 = Bt + (size_t)(n0 + srow + 128) * K + scol;
  const int sw = (g ^ ((r16 >> 1) & 3)) * 8;               // T2 read XOR
  const int a_off = (wr * 128 + r16) * 32 + sw;
  const int b_off = (wc * 64 + r16) * 32 + sw;

  floatx4 acc[8][4] = {};

#define STBL(s0, s1, pb) do { gload16((s0), Bs + (pb) * 8192 + wsl); \
                              gload16((s1), Bs + (pb) * 8192 + wsl + 4096); } while (0)
#define STAL(s0, s1, pb) do { gload16((s0), As + (pb) * 8192 + wsl); \
                              gload16((s1), As + (pb) * 8192 + wsl + 4096); } while (0)

  STBL(bt, bt1, 0);
  STAL(at, at1, 0);
  STBL(bt + 32, bt1 + 32, 1);
  asm volatile("s_waitcnt vmcnt(2)" ::: "memory");
  __builtin_amdgcn_s_barrier();

  for (int t = 0; t < numK; ++t) {
    const int p = t & 1, pn = p ^ 1;
    bf16x8 af[4], bfr[4];

    // ---- phase 0: mgroup 0 ----
    #pragma unroll
    for (int j = 0; j < 4; ++j) bfr[j] = *(const bf16x8*)&Bs[p * 8192 + b_off + j * 512];
    #pragma unroll
    for (int i = 0; i < 4; ++i) af[i] = *(const bf16x8*)&As[p * 8192 + a_off + i * 512];
    if (t + 1 < numK) STAL(at + 32, at1 + 32, pn);
    __builtin_amdgcn_s_barrier();
    asm volatile("s_waitcnt lgkmcnt(0)" ::: "memory");
    __builtin_amdgcn_s_setprio(1);
    #pragma unroll
    for (int i = 0; i < 4; ++i)
      #pragma unroll
      for (int j = 0; j < 4; ++j)
        acc[i][j] = __builtin_amdgcn_mfma_f32_16x16x32_bf16(af[i], bfr[j], acc[i][j], 0, 0, 0);
    __builtin_amdgcn_s_setprio(0);
    __builtin_amdgcn_s_barrier();

    // ---- phase 1: mgroup 1 (B regs reused) ----
    #pragma unroll
    for (int i = 0; i < 4; ++i) af[i] = *(const bf16x8*)&As[p * 8192 + a_off + (i + 4) * 512];
    if (t + 2 < numK) STBL(bt + 64, bt1 + 64, p);
    __builtin_amdgcn_s_barrier();
    asm volatile("s_waitcnt lgkmcnt(0)" ::: "memory");
    __builtin_amdgcn_s_setprio(1);
    #pragma unroll
    for (int i = 0; i < 4; ++i)
      #pragma unroll
      for (int j = 0; j < 4; ++j)
        acc[i + 4][j] = __builtin_amdgcn_mfma_f32_16x16x32_bf16(af[i], bfr[j], acc[i + 4][j], 0, 0, 0);
    __builtin_amdgcn_s_setprio(0);
    if (t + 2 < numK) { asm volatile("s_waitcnt vmcnt(2)" ::: "memory"); }
    else              { asm volatile("s_waitcnt vmcnt(0)" ::: "memory"); }
    __builtin_amdgcn_s_barrier();

    at += 32; at1 += 32; bt += 32; bt1 += 32;
  }
#undef STBL
#undef STAL

  // epilogue: wave-private LDS transpose (f32, stride 68) -> contiguous 16B stores
  float* sb = reinterpret_cast<float*>(smem) + wave * 1088;  // 16 rows x 68
  const int seg = lane & 15, rq = lane >> 4;
  const int mrow_base = m0 + wr * 128;
  const int ncol_base = n0 + wc * 64;
  #pragma unroll
  for (int mf = 0; mf < 8; ++mf) {
    #pragma unroll
    for (int nf = 0; nf < 4; ++nf) {
      #pragma unroll
      for (int q = 0; q < 4; ++q)
        sb[(g * 4 + q) * 68 + nf * 16 + r16] = acc[mf][nf][q];
    }
    #pragma unroll
    for (int pz = 0; pz < 4; ++pz) {
      int row = rq + pz * 4;
      floatx4 v = *reinterpret_cast<const floatx4*>(&sb[row * 68 + seg * 4]);
      int m = mrow_base + mf * 16 + row;
      int n = ncol_base + seg * 4;
      if (n + 4 <= N) {
        __builtin_memcpy(&Cf[(size_t)m * N + n], &v, 16);
      } else {
        #pragma unroll
        for (int e = 0; e < 4; ++e)
          if (n + e < N) Cf[(size_t)m * N + n + e] = v[e];
      }
    }
  }
}

// ================= TBMx256 BK=32 pipelined MFMA GEMM (qkv / fc) =================
template<int TBM, int EPI>   // EPI: 3 +bias+gelu ->bf16, 4 +bias ->bf16
__global__ __launch_bounds__(512, 1) void k_gemm8(
    const bf16* __restrict__ A, const bf16* __restrict__ Bt,
    const float* __restrict__ bias,
    float* __restrict__ Cf, bf16* __restrict__ Cb,
    int N, int K) {
  constexpr int MI = TBM / 32;
  constexpr int MH = MI / 2;
  constexpr int MTILES = 4096 / TBM;
  __shared__ __align__(16) bf16 smem[2 * 8192 + 2 * TBM * 32];
  bf16* Bs = smem;
  bf16* As = smem + 2 * 8192;
  const int nwg = gridDim.x;
  const int id = blockIdx.x;
  const int swz = (id & 7) * (nwg >> 3) + (id >> 3);
  const int m0 = (swz % MTILES) * TBM;
  const int n0 = (swz / MTILES) * 256;
  const int tid = threadIdx.x, lane = tid & 63, wave = tid >> 6;
  const int wr = wave >> 2, wc = wave & 3;
  const int g = lane >> 4, r16 = lane & 15;
  const int numK = K >> 5;
  const int wsl = wave * 512;

  const int srow = wave * 16 + (lane >> 2);
  const int scol = ((lane & 3) ^ ((lane >> 3) & 3)) * 8;
  const bf16* at  = A  + (size_t)(m0 + srow) * K + scol;
  const bf16* at1 = A  + (size_t)(m0 + srow + 128) * K + scol;
  const bf16* bt  = Bt + (size_t)(n0 + srow) * K + scol;
  const bf16* bt1 = Bt + (size_t)(n0 + srow + 128) * K + scol;
  const int sw = (g ^ ((r16 >> 1) & 3)) * 8;
  const int a_off = (wr * (TBM / 2) + r16) * 32 + sw;
  const int b_off = (wc * 64 + r16) * 32 + sw;

  floatx4 acc[MI][4] = {};

#define STB(s0, s1, pb) do { gload16((s0), Bs + (pb) * 8192 + wsl); \
                             gload16((s1), Bs + (pb) * 8192 + wsl + 4096); } while (0)
#define STA(s0, s1, pb) do { gload16((s0), As + (pb) * TBM * 32 + wsl); \
                             if constexpr (TBM == 256) gload16((s1), As + (pb) * TBM * 32 + wsl + 4096); } while (0)

  STB(bt, bt1, 0);
  STA(at, at1, 0);
  STB(bt + 32, bt1 + 32, 1);
  asm volatile("s_waitcnt vmcnt(2)" ::: "memory");
  __builtin_amdgcn_s_barrier();

  for (int t = 0; t < numK; ++t) {
    const int p = t & 1, pn = p ^ 1;
    bf16x8 af[MH], bfr[4];

    #pragma unroll
    for (int j = 0; j < 4; ++j) bfr[j] = *(const bf16x8*)&Bs[p * 8192 + b_off + j * 512];
    #pragma unroll
    for (int i = 0; i < MH; ++i) af[i] = *(const bf16x8*)&As[p * TBM * 32 + a_off + i * 512];
    if (t + 1 < numK) STA(at + 32, at1 + 32, pn);
    __builtin_amdgcn_s_barrier();
    asm volatile("s_waitcnt lgkmcnt(0)" ::: "memory");
    __builtin_amdgcn_s_setprio(1);
    #pragma unroll
    for (int i = 0; i < MH; ++i)
      #pragma unroll
      for (int j = 0; j < 4; ++j)
        acc[i][j] = __builtin_amdgcn_mfma_f32_16x16x32_bf16(af[i], bfr[j], acc[i][j], 0, 0, 0);
    __builtin_amdgcn_s_setprio(0);
    __builtin_amdgcn_s_barrier();

    #pragma unroll
    for (int i = 0; i < MH; ++i) af[i] = *(const bf16x8*)&As[p * TBM * 32 + a_off + (i + MH) * 512];
    if (t + 2 < numK) STB(bt + 64, bt1 + 64, p);
    __builtin_amdgcn_s_barrier();
    asm volatile("s_waitcnt lgkmcnt(0)" ::: "memory");
    __builtin_amdgcn_s_setprio(1);
    #pragma unroll
    for (int i = 0; i < MH; ++i)
      #pragma unroll
      for (int j = 0; j < 4; ++j)
        acc[i + MH][j] = __builtin_amdgcn_mfma_f32_16x16x32_bf16(af[i], bfr[j], acc[i + MH][j], 0, 0, 0);
    __builtin_amdgcn_s_setprio(0);
    if (t + 2 < numK) { asm volatile("s_waitcnt vmcnt(2)" ::: "memory"); }
    else              { asm volatile("s_waitcnt vmcnt(0)" ::: "memory"); }
    __builtin_amdgcn_s_barrier();

    at += 32; at1 += 32; bt += 32; bt1 += 32;
  }
#undef STB
#undef STA

  bf16* sb = smem + wave * 1152;
  const int rr_rd = lane & 15, seg = lane >> 4;
  const int nb = n0 + wc * 64 + r16;
  float bv[4];
  #pragma unroll
  for (int j = 0; j < 4; ++j) bv[j] = bias[nb + j * 16];
  #pragma unroll
  for (int mf = 0; mf < MI; ++mf) {
    #pragma unroll
    for (int j = 0; j < 4; ++j) {
      #pragma unroll
      for (int q = 0; q < 4; ++q) {
        float v = acc[mf][j][q] + bv[j];
        if (EPI == 3) v = gelu_f(v);
        sb[(g * 4 + q) * 72 + j * 16 + r16] = (bf16)v;
      }
    }
    bf16x8 o0 = *(const bf16x8*)&sb[rr_rd * 72 + seg * 16];
    bf16x8 o1 = *(const bf16x8*)&sb[rr_rd * 72 + seg * 16 + 8];
    size_t orow = (size_t)(m0 + wr * (TBM / 2) + mf * 16 + rr_rd) * N + (n0 + wc * 64 + seg * 16);
    *(bf16x8*)&Cb[orow] = o0;
    *(bf16x8*)&Cb[orow + 8] = o1;
  }
}

// ================= 64x128 BK=32 pipelined GEMM, 4 waves (proj / fcp) =================
// bias + residual in-place f32. acc 32 AGPR -> ~4 blocks/CU; grid 384.
// Same proven skeleton: 2-phase, T2 swizzle pair, counted vmcnt(2), setprio.
__global__ __launch_bounds__(256, 4) void k_gemmp2(
    const bf16* __restrict__ A, const bf16* __restrict__ Bt,
    const float* __restrict__ bias, float* __restrict__ Cf,
    int N, int K) {
  __shared__ __align__(16) bf16 smem[2 * 2048 + 2 * 4096];   // A: 2x2048, B: 2x4096
  bf16* As = smem;
  bf16* Bs = smem + 2 * 2048;
  const int nwg = gridDim.x;   // 384, %8==0
  const int id = blockIdx.x;
  const int swz = (id & 7) * (nwg >> 3) + (id >> 3);
  const int m0 = (swz & 63) * 64;    // 64 m-tiles
  const int n0 = (swz >> 6) * 128;
  const int tid = threadIdx.x, lane = tid & 63, wave = tid >> 6;
  const int wr = wave >> 1, wc = wave & 1;   // 2M x 2N; wave tile 32x64
  const int g = lane >> 4, r16 = lane & 15;
  const int numK = K >> 5;
  const int wsl = wave * 512;

  const int srow = wave * 16 + (lane >> 2);            // 0..63
  const int scol = ((lane & 3) ^ ((lane >> 3) & 3)) * 8;
  const bf16* at  = A  + (size_t)(m0 + srow) * K + scol;
  const bf16* bt  = Bt + (size_t)(n0 + srow) * K + scol;
  const bf16* bt1 = Bt + (size_t)(n0 + srow + 64) * K + scol;
  const int sw = (g ^ ((r16 >> 1) & 3)) * 8;
  const int a_off = (wr * 32 + r16) * 32 + sw;
  const int b_off = (wc * 64 + r16) * 32 + sw;

  floatx4 acc[2][4] = {};

#define STAq(s0, pb) gload16((s0), As + (pb) * 2048 + wsl)
#define STBq(s0, s1, pb) do { gload16((s0), Bs + (pb) * 4096 + wsl); \
                              gload16((s1), Bs + (pb) * 4096 + 2048 + wsl); } while (0)

  STBq(bt, bt1, 0);
  STAq(at, 0);
  STBq(bt + 32, bt1 + 32, 1);
  asm volatile("s_waitcnt vmcnt(2)" ::: "memory");
  __builtin_amdgcn_s_barrier();

  for (int t = 0; t < numK; ++t) {
    const int p = t & 1, pn = p ^ 1;
    bf16x8 af, bfr[4];

    // ---- phase 0: mgroup 0 ----
    #pragma unroll
    for (int j = 0; j < 4; ++j) bfr[j] = *(const bf16x8*)&Bs[p * 4096 + b_off + j * 512];
    af = *(const bf16x8*)&As[p * 2048 + a_off];
    if (t + 1 < numK) STAq(at + 32, pn);
    __builtin_amdgcn_s_barrier();
    asm volatile("s_waitcnt lgkmcnt(0)" ::: "memory");
    __builtin_amdgcn_s_setprio(1);
    #pragma unroll
    for (int j = 0; j < 4; ++j)
      acc[0][j] = __builtin_amdgcn_mfma_f32_16x16x32_bf16(af, bfr[j], acc[0][j], 0, 0, 0);
    __builtin_amdgcn_s_setprio(0);
    __builtin_amdgcn_s_barrier();

    // ---- phase 1: mgroup 1 (B regs reused) ----
    af = *(const bf16x8*)&As[p * 2048 + a_off + 512];
    if (t + 2 < numK) STBq(bt + 64, bt1 + 64, p);
    __builtin_amdgcn_s_barrier();
    asm volatile("s_waitcnt lgkmcnt(0)" ::: "memory");
    __builtin_amdgcn_s_setprio(1);
    #pragma unroll
    for (int j = 0; j < 4; ++j)
      acc[1][j] = __builtin_amdgcn_mfma_f32_16x16x32_bf16(af, bfr[j], acc[1][j], 0, 0, 0);
    __builtin_amdgcn_s_setprio(0);
    if (t + 2 < numK) { asm volatile("s_waitcnt vmcnt(2)" ::: "memory"); }
    else              { asm volatile("s_waitcnt vmcnt(0)" ::: "memory"); }
    __builtin_amdgcn_s_barrier();

    at += 32; bt += 32; bt1 += 32;
  }
#undef STAq
#undef STBq

  // epilogue: bias + residual, scalar f32 (16 lanes = one aligned 64B line)
  const int mb = m0 + wr * 32 + g * 4;
  const int nb = n0 + wc * 64 + r16;
  #pragma unroll
  for (int j = 0; j < 4; ++j) {
    int n = nb + j * 16;
    float bv = bias[n];
    #pragma unroll
    for (int i = 0; i < 2; ++i) {
      #pragma unroll
      for (int q = 0; q < 4; ++q) {
        int m = mb + i * 16 + q;
        size_t o = (size_t)m * N + n;
        Cf[o] = Cf[o] + acc[i][j][q] + bv;
      }
    }
  }
}

// ---------------- V transpose: qkv_bf V-part -> vt[bh][d][t] bf16 ----------------
__global__ __launch_bounds__(256) void k_vtrans(const bf16* __restrict__ qkv, bf16* __restrict__ vt) {
  __shared__ bf16 tile[64][72];
  int bh = blockIdx.x, t0 = blockIdx.y * 64;
  int b = bh / HNUM, h = bh % HNUM;
  int tid = threadIdx.x;
  int r8 = tid >> 3, s8 = tid & 7;
  #pragma unroll
  for (int p = 0; p < 2; ++p) {
    int row = p * 32 + r8;
    uint4 v = *reinterpret_cast<const uint4*>(
        qkv + (size_t)(b * TDIM + t0 + row) * (3 * CDIM) + 2 * CDIM + h * 64 + s8 * 8);
    *reinterpret_cast<uint4*>(&tile[row][s8 * 8]) = v;
  }
  __syncthreads();
  int d = tid >> 2, q4 = tid & 3;
  #pragma unroll
  for (int half = 0; half < 2; ++half) {
    int t = q4 * 16 + half * 8;
    bf16x8 o;
    #pragma unroll
    for (int u = 0; u < 8; ++u) o[u] = tile[t + u][d];
    *reinterpret_cast<bf16x8*>(vt + (size_t)bh * (64 * TDIM) + (size_t)d * TDIM + t0 + t) = o;
  }
}

// ---------------- MFMA flash attention (QBLK=64, 4 waves — r8 proven) ----------------
__global__ __launch_bounds__(256) void k_attn(const bf16* __restrict__ qkv,
                                              const bf16* __restrict__ vt,
                                              bf16* __restrict__ y) {
  __shared__ __align__(16) bf16 Ks[64 * 64];
  __shared__ __align__(16) bf16 Vs[64 * 64];
  __shared__ __align__(16) bf16 Ps[64 * 64];
  const int bh = blockIdx.x, qt = blockIdx.y;
  const int b = bh / HNUM, h = bh % HNUM;
  const int tid = threadIdx.x, lane = tid & 63, wave = tid >> 6;
  const int g = lane >> 4, r16 = lane & 15;
  const int w16 = wave * 16;
  const int r8 = tid >> 3, s8 = tid & 7;

  bf16x8 qf[2];
  {
    const bf16* qsrc = qkv + (size_t)(b * TDIM + qt * 64 + w16 + r16) * (3 * CDIM) + h * 64 + g * 8;
    qf[0] = *reinterpret_cast<const bf16x8*>(qsrc);
    qf[1] = *reinterpret_cast<const bf16x8*>(qsrc + 32);
  }

  float m_r[4], l_r[4];
  floatx4 yacc[4] = {};
  #pragma unroll
  for (int q = 0; q < 4; ++q) { m_r[q] = -1e30f; l_r[q] = 0.f; }

  for (int kt = 0; kt <= qt; ++kt) {
    __syncthreads();
    #pragma unroll
    for (int p = 0; p < 2; ++p) {
      int row = p * 32 + r8;
      uint4 kv = *reinterpret_cast<const uint4*>(
          qkv + (size_t)(b * TDIM + kt * 64 + row) * (3 * CDIM) + CDIM + h * 64 + s8 * 8);
      *reinterpret_cast<uint4*>(&Ks[row * 64 + ((s8 ^ (row & 7)) * 8)]) = kv;
      uint4 vv = *reinterpret_cast<const uint4*>(
          vt + (size_t)bh * (64 * TDIM) + (size_t)row * TDIM + kt * 64 + s8 * 8);
      *reinterpret_cast<uint4*>(&Vs[row * 64 + ((s8 ^ (row & 7)) * 8)]) = vv;
    }
    __syncthreads();

    floatx4 sa[4] = {};
    #pragma unroll
    for (int c = 0; c < 2; ++c) {
      bf16x8 kf[4];
      #pragma unroll
      for (int j = 0; j < 4; ++j) {
        int krow = j * 16 + r16;
        kf[j] = *reinterpret_cast<const bf16x8*>(&Ks[krow * 64 + (((g + 4 * c) ^ (krow & 7)) * 8)]);
      }
      #pragma unroll
      for (int j = 0; j < 4; ++j)
        sa[j] = __builtin_amdgcn_mfma_f32_16x16x32_bf16(qf[c], kf[j], sa[j], 0, 0, 0);
    }

    const bool diag = (kt == qt);
    float p_v[4][4];
    #pragma unroll
    for (int q = 0; q < 4; ++q) {
      int qrow = w16 + g * 4 + q;
      float mx = -1e30f;
      #pragma unroll
      for (int j = 0; j < 4; ++j) {
        float s = sa[j][q] * 0.125f;
        if (diag && (r16 + j * 16) > qrow) s = -1e30f;
        p_v[j][q] = s;
        mx = fmaxf(mx, s);
      }
      #pragma unroll
      for (int o = 1; o < 16; o <<= 1) mx = fmaxf(mx, __shfl_xor(mx, o));
      float mnew = fmaxf(m_r[q], mx);
      float ps = 0.f;
      #pragma unroll
      for (int j = 0; j < 4; ++j) {
        float p = __expf(p_v[j][q] - mnew);
        p_v[j][q] = p;
        ps += p;
      }
      #pragma unroll
      for (int o = 1; o < 16; o <<= 1) ps += __shfl_xor(ps, o);
      float alpha = __expf(m_r[q] - mnew);
      m_r[q] = mnew;
      l_r[q] = l_r[q] * alpha + ps;
      #pragma unroll
      for (int j = 0; j < 4; ++j) yacc[j][q] *= alpha;
      #pragma unroll
      for (int j = 0; j < 4; ++j) {
        int col = r16 + j * 16;
        Ps[qrow * 64 + (col ^ ((qrow & 7) << 3))] = (bf16)p_v[j][q];
      }
    }

    #pragma unroll
    for (int ks = 0; ks < 2; ++ks) {
      int prow = w16 + r16;
      bf16x8 pa = *reinterpret_cast<const bf16x8*>(&Ps[prow * 64 + (((g + 4 * ks) ^ (prow & 7)) * 8)]);
      #pragma unroll
      for (int j = 0; j < 4; ++j) {
        int vrow = j * 16 + r16;
        bf16x8 vb = *reinterpret_cast<const bf16x8*>(&Vs[vrow * 64 + (((g + 4 * ks) ^ (vrow & 7)) * 8)]);
        yacc[j] = __builtin_amdgcn_mfma_f32_16x16x32_bf16(pa, vb, yacc[j], 0, 0, 0);
      }
    }
  }

  #pragma unroll
  for (int q = 0; q < 4; ++q) {
    float inv = 1.0f / l_r[q];
    int tok = b * TDIM + qt * 64 + w16 + g * 4 + q;
    #pragma unroll
    for (int j = 0; j < 4; ++j)
      y[(size_t)tok * CDIM + h * 64 + r16 + j * 16] = (bf16)(yacc[j][q] * inv);
  }
}

// ---------------- launcher ----------------
extern "C" void kernel_launch(void* const* d_in, const int* in_sizes, int n_in,
                              void* d_out, int out_size, void* d_ws, size_t ws_size,
                              hipStream_t stream) {
  (void)in_sizes; (void)n_in; (void)out_size;
  const int*   idx    = (const int*)  d_in[0];
  const float* wte    = (const float*)d_in[1];
  const float* wpe    = (const float*)d_in[2];
  const float* ln1_s  = (const float*)d_in[3];
  const float* ln1_b  = (const float*)d_in[4];
  const float* qkv_w  = (const float*)d_in[5];
  const float* qkv_b  = (const float*)d_in[6];
  const float* proj_w = (const float*)d_in[7];
  const float* proj_b = (const float*)d_in[8];
  const float* ln2_s  = (const float*)d_in[9];
  const float* ln2_b  = (const float*)d_in[10];
  const float* fc_w   = (const float*)d_in[11];
  const float* fc_b   = (const float*)d_in[12];
  const float* fcp_w  = (const float*)d_in[13];
  const float* fcp_b  = (const float*)d_in[14];
  const float* lnf_s  = (const float*)d_in[15];
  const float* lnf_b  = (const float*)d_in[16];
  float* logits = (float*)d_out;

  char* base = (char*)d_ws;
  size_t off = 0;
  auto alloc = [&](size_t bytes) -> void* {
    void* p = base + off;
    off += (bytes + 255) & ~(size_t)255;
    return p;
  };
  bf16*  wte_bf  = (bf16*) alloc((size_t)VDIM * CDIM * 2);   // keep FIRST (logits B-tail overreads land in ws)
  bf16*  wq_all  = (bf16*) alloc((size_t)LNUM * 3 * CDIM * CDIM * 2);
  bf16*  wp_all  = (bf16*) alloc((size_t)LNUM * CDIM * CDIM * 2);
  bf16*  wf_all  = (bf16*) alloc((size_t)LNUM * 4 * CDIM * CDIM * 2);
  bf16*  wfp_all = (bf16*) alloc((size_t)LNUM * 4 * CDIM * CDIM * 2);
  float* x       = (float*)alloc((size_t)NTOK * CDIM * 4);
  bf16*  hb      = (bf16*) alloc((size_t)NTOK * CDIM * 2);
  bf16*  qkv_bf  = (bf16*) alloc((size_t)NTOK * 3 * CDIM * 2);
  bf16*  vt      = (bf16*) alloc((size_t)BDIM * HNUM * 64 * TDIM * 2);
  bf16*  yb      = (bf16*) alloc((size_t)NTOK * CDIM * 2);
  bf16*  gb      = (bf16*) alloc((size_t)NTOK * 4 * CDIM * 2);
  if (off > ws_size) return;

  k_cvt_bf16<<<4096, 256, 0, stream>>>(wte, wte_bf, (long)VDIM * CDIM);
  k_trans_all<<<LNUM * TILES_LAYER, 256, 0, stream>>>(qkv_w, proj_w, fc_w, fcp_w,
                                                      wq_all, wp_all, wf_all, wfp_all);
  k_embed<<<NTOK, 256, 0, stream>>>(idx, wte, wpe, x);

  for (int l = 0; l < LNUM; ++l) {
    const bf16* wq  = wq_all  + (size_t)l * 3 * CDIM * CDIM;
    const bf16* wp  = wp_all  + (size_t)l * CDIM * CDIM;
    const bf16* wf  = wf_all  + (size_t)l * 4 * CDIM * CDIM;
    const bf16* wfp = wfp_all + (size_t)l * 4 * CDIM * CDIM;

    k_layernorm<<<NTOK, 256, 0, stream>>>(x, ln1_s + l*CDIM, ln1_b + l*CDIM, hb);
    k_gemm8<128,4><<<32 * 9, 512, 0, stream>>>(hb, wq, qkv_b + (size_t)l*3*CDIM, nullptr, qkv_bf, 3*CDIM, CDIM);
    k_vtrans<<<dim3(BDIM*HNUM, TDIM/64), 256, 0, stream>>>(qkv_bf, vt);
    k_attn<<<dim3(BDIM*HNUM, TDIM/64), 256, 0, stream>>>(qkv_bf, vt, yb);
    k_gemmp2<<<64 * 6, 256, 0, stream>>>(yb, wp, proj_b + (size_t)l*CDIM, x, CDIM, CDIM);
    k_layernorm<<<NTOK, 256, 0, stream>>>(x, ln2_s + l*CDIM, ln2_b + l*CDIM, hb);
    k_gemm8<128,3><<<32 * 12, 512, 0, stream>>>(hb, wf, fc_b + (size_t)l*4*CDIM, nullptr, gb, 4*CDIM, CDIM);
    k_gemmp2<<<64 * 6, 256, 0, stream>>>(gb, wfp, fcp_b + (size_t)l*CDIM, x, CDIM, 4*CDIM);
  }

  k_layernorm<<<NTOK, 256, 0, stream>>>(x, lnf_s, lnf_b, hb);
  int ntile = (VDIM + 255) / 256;  // 197; tail guarded, staging overreads stay in ws
  k_gemm_logits<<<16 * ntile, 512, 0, stream>>>(hb, wte_bf, logits, VDIM, CDIM);
}

// Round 13
// 1781.918 us; speedup vs baseline: 1.0560x; 1.0079x over previous
//
#include <hip/hip_runtime.h>
#include <math.h>

#define LNUM 6
#define HNUM 12
#define CDIM 768
#define VDIM 50257
#define BDIM 4
#define TDIM 1024
#define NTOK 4096   // B*T

typedef __bf16 bf16;
typedef __bf16 bf16x8 __attribute__((ext_vector_type(8)));
typedef float  floatx4 __attribute__((ext_vector_type(4)));
typedef unsigned int u32;

// async global->LDS, 16B per lane. LDS dest must be wave-uniform base; HW adds lane*16.
__device__ inline void gload16(const bf16* gsrc, bf16* lds) {
  __builtin_amdgcn_global_load_lds(
      (const __attribute__((address_space(1))) u32*)gsrc,
      (__attribute__((address_space(3))) u32*)lds, 16, 0, 0);
}

// ---------------- fp32 -> bf16 bulk convert (wte) ----------------
__global__ void k_cvt_bf16(const float* __restrict__ in, bf16* __restrict__ out, long n) {
  long i = ((long)blockIdx.x * blockDim.x + threadIdx.x) * 4;
  long stride = (long)gridDim.x * blockDim.x * 4;
  for (; i < n; i += stride) {
    float4 v = *reinterpret_cast<const float4*>(in + i);
    bf16 b0 = (bf16)v.x, b1 = (bf16)v.y, b2 = (bf16)v.z, b3 = (bf16)v.w;
    ushort4 pk;
    pk.x = __builtin_bit_cast(unsigned short, b0);
    pk.y = __builtin_bit_cast(unsigned short, b1);
    pk.z = __builtin_bit_cast(unsigned short, b2);
    pk.w = __builtin_bit_cast(unsigned short, b3);
    *reinterpret_cast<ushort4*>(out + i) = pk;
  }
}

// -------- batched transpose+convert for ALL layer weights (one launch) --------
#define TILES_QKV  1728
#define TILES_PROJ 576
#define TILES_FC   2304
#define TILES_FCP  2304
#define TILES_LAYER (TILES_QKV + TILES_PROJ + TILES_FC + TILES_FCP)

__global__ __launch_bounds__(256) void k_trans_all(
    const float* __restrict__ qkv_w, const float* __restrict__ proj_w,
    const float* __restrict__ fc_w, const float* __restrict__ fcp_w,
    bf16* __restrict__ wq, bf16* __restrict__ wp,
    bf16* __restrict__ wf, bf16* __restrict__ wfp) {
  __shared__ float tile[32][33];
  int bid = blockIdx.x;
  int layer = bid / TILES_LAYER, r = bid % TILES_LAYER;
  const float* src; bf16* dst; int K, N, tx, ty;
  if (r < TILES_QKV) {
    src = qkv_w + (size_t)layer * CDIM * 3 * CDIM; dst = wq + (size_t)layer * CDIM * 3 * CDIM;
    K = CDIM; N = 3 * CDIM; tx = r % 72; ty = r / 72;
  } else if (r < TILES_QKV + TILES_PROJ) {
    r -= TILES_QKV;
    src = proj_w + (size_t)layer * CDIM * CDIM; dst = wp + (size_t)layer * CDIM * CDIM;
    K = CDIM; N = CDIM; tx = r % 24; ty = r / 24;
  } else if (r < TILES_QKV + TILES_PROJ + TILES_FC) {
    r -= TILES_QKV + TILES_PROJ;
    src = fc_w + (size_t)layer * CDIM * 4 * CDIM; dst = wf + (size_t)layer * CDIM * 4 * CDIM;
    K = CDIM; N = 4 * CDIM; tx = r % 96; ty = r / 96;
  } else {
    r -= TILES_QKV + TILES_PROJ + TILES_FC;
    src = fcp_w + (size_t)layer * 4 * CDIM * CDIM; dst = wfp + (size_t)layer * 4 * CDIM * CDIM;
    K = 4 * CDIM; N = CDIM; tx = r % 24; ty = r / 24;
  }
  int n0 = tx * 32, k0 = ty * 32;
  int nx = threadIdx.x & 31, tyy = threadIdx.x >> 5;
  #pragma unroll
  for (int p = 0; p < 4; ++p) {
    int k = tyy + p * 8;
    tile[k][nx] = src[(size_t)(k0 + k) * N + n0 + nx];
  }
  __syncthreads();
  #pragma unroll
  for (int p = 0; p < 4; ++p) {
    int n = tyy + p * 8;
    dst[(size_t)(n0 + n) * K + k0 + nx] = (bf16)tile[nx][n];
  }
}

// ---------------- embedding ----------------
__global__ void k_embed(const int* __restrict__ idx, const float* __restrict__ wte,
                        const float* __restrict__ wpe, float* __restrict__ x) {
  int tok = blockIdx.x;
  int t = tok & (TDIM - 1);
  int id = idx[tok];
  const float* a = wte + (size_t)id * CDIM;
  const float* p = wpe + (size_t)t * CDIM;
  float* o = x + (size_t)tok * CDIM;
  for (int c = threadIdx.x; c < CDIM; c += 256) o[c] = a[c] + p[c];
}

// ---------------- layernorm: fp32 in -> bf16 out ----------------
__global__ __launch_bounds__(256) void k_layernorm(const float* __restrict__ x,
    const float* __restrict__ sc, const float* __restrict__ bi, bf16* __restrict__ out) {
  __shared__ float red[8];
  int row = blockIdx.x;
  const float* xr = x + (size_t)row * CDIM;
  int t = threadIdx.x;
  float v0 = xr[t], v1 = xr[t + 256], v2 = xr[t + 512];
  float s = v0 + v1 + v2;
  #pragma unroll
  for (int o = 32; o > 0; o >>= 1) s += __shfl_down(s, o);
  if ((t & 63) == 0) red[t >> 6] = s;
  __syncthreads();
  float mean = (red[0] + red[1] + red[2] + red[3]) * (1.0f / CDIM);
  float d0 = v0 - mean, d1 = v1 - mean, d2 = v2 - mean;
  float q = d0 * d0 + d1 * d1 + d2 * d2;
  #pragma unroll
  for (int o = 32; o > 0; o >>= 1) q += __shfl_down(q, o);
  if ((t & 63) == 0) red[4 + (t >> 6)] = q;
  __syncthreads();
  float var = (red[4] + red[5] + red[6] + red[7]) * (1.0f / CDIM);
  float rs = rsqrtf(var + 1e-5f);
  bf16* orow = out + (size_t)row * CDIM;
  orow[t]       = (bf16)(d0 * rs * sc[t]       + bi[t]);
  orow[t + 256] = (bf16)(d1 * rs * sc[t + 256] + bi[t + 256]);
  orow[t + 512] = (bf16)(d2 * rs * sc[t + 512] + bi[t + 512]);
}

__device__ inline float gelu_f(float x) {
  float x3 = x * x * x;
  return 0.5f * x * (1.0f + tanhf(0.7978845608028654f * (x + 0.044715f * x3)));
}

// ================= 256x256 BK=32 logits GEMM (r8-proven config) =================
// 8 waves, A/B 2-buf, vmcnt(2), T2 swizzle pair, f32 LDS-transpose epilogue.
__global__ __launch_bounds__(512, 1) void k_gemm_logits(
    const bf16* __restrict__ A, const bf16* __restrict__ Bt,
    float* __restrict__ Cf, int N, int K) {
  __shared__ __align__(16) bf16 smem[4 * 8192];
  bf16* Bs = smem;             // [2][8192]
  bf16* As = smem + 2 * 8192;  // [2][8192]
  const int nwg = gridDim.x;   // 3152, %8==0
  const int id = blockIdx.x;
  const int swz = (id & 7) * (nwg >> 3) + (id >> 3);
  const int m0 = (swz & 15) * 256;
  const int n0 = (swz >> 4) * 256;
  const int tid = threadIdx.x, lane = tid & 63, wave = tid >> 6;
  const int wr = wave >> 2, wc = wave & 3;
  const int g = lane >> 4, r16 = lane & 15;
  const int numK = K >> 5;
  const int wsl = wave * 512;

  const int srow = wave * 16 + (lane >> 2);
  const int scol = ((lane & 3) ^ ((lane >> 3) & 3)) * 8;   // T2 source permute
  const bf16* at  = A  + (size_t)(m0 + srow) * K + scol;
  const bf16* at1 = A  + (size_t)(m0 + srow + 128) * K + scol;
  const bf16* bt  = Bt + (size_t)(n0 + srow) * K + scol;
  const bf16* bt1 = Bt + (size_t)(n0 + srow + 128) * K + scol;
  const int sw = (g ^ ((r16 >> 1) & 3)) * 8;               // T2 read XOR
  const int a_off = (wr * 128 + r16) * 32 + sw;
  const int b_off = (wc * 64 + r16) * 32 + sw;

  floatx4 acc[8][4] = {};

#define STBL(s0, s1, pb) do { gload16((s0), Bs + (pb) * 8192 + wsl); \
                              gload16((s1), Bs + (pb) * 8192 + wsl + 4096); } while (0)
#define STAL(s0, s1, pb) do { gload16((s0), As + (pb) * 8192 + wsl); \
                              gload16((s1), As + (pb) * 8192 + wsl + 4096); } while (0)

  STBL(bt, bt1, 0);
  STAL(at, at1, 0);
  STBL(bt + 32, bt1 + 32, 1);
  asm volatile("s_waitcnt vmcnt(2)" ::: "memory");
  __builtin_amdgcn_s_barrier();

  for (int t = 0; t < numK; ++t) {
    const int p = t & 1, pn = p ^ 1;
    bf16x8 af[4], bfr[4];

    // ---- phase 0: mgroup 0 ----
    #pragma unroll
    for (int j = 0; j < 4; ++j) bfr[j] = *(const bf16x8*)&Bs[p * 8192 + b_off + j * 512];
    #pragma unroll
    for (int i = 0; i < 4; ++i) af[i] = *(const bf16x8*)&As[p * 8192 + a_off + i * 512];
    if (t + 1 < numK) STAL(at + 32, at1 + 32, pn);
    __builtin_amdgcn_s_barrier();
    asm volatile("s_waitcnt lgkmcnt(0)" ::: "memory");
    __builtin_amdgcn_s_setprio(1);
    #pragma unroll
    for (int i = 0; i < 4; ++i)
      #pragma unroll
      for (int j = 0; j < 4; ++j)
        acc[i][j] = __builtin_amdgcn_mfma_f32_16x16x32_bf16(af[i], bfr[j], acc[i][j], 0, 0, 0);
    __builtin_amdgcn_s_setprio(0);
    __builtin_amdgcn_s_barrier();

    // ---- phase 1: mgroup 1 (B regs reused) ----
    #pragma unroll
    for (int i = 0; i < 4; ++i) af[i] = *(const bf16x8*)&As[p * 8192 + a_off + (i + 4) * 512];
    if (t + 2 < numK) STBL(bt + 64, bt1 + 64, p);
    __builtin_amdgcn_s_barrier();
    asm volatile("s_waitcnt lgkmcnt(0)" ::: "memory");
    __builtin_amdgcn_s_setprio(1);
    #pragma unroll
    for (int i = 0; i < 4; ++i)
      #pragma unroll
      for (int j = 0; j < 4; ++j)
        acc[i + 4][j] = __builtin_amdgcn_mfma_f32_16x16x32_bf16(af[i], bfr[j], acc[i + 4][j], 0, 0, 0);
    __builtin_amdgcn_s_setprio(0);
    if (t + 2 < numK) { asm volatile("s_waitcnt vmcnt(2)" ::: "memory"); }
    else              { asm volatile("s_waitcnt vmcnt(0)" ::: "memory"); }
    __builtin_amdgcn_s_barrier();

    at += 32; at1 += 32; bt += 32; bt1 += 32;
  }
#undef STBL
#undef STAL

  // epilogue: wave-private LDS transpose (f32, stride 68) -> contiguous 16B stores
  float* sb = reinterpret_cast<float*>(smem) + wave * 1088;  // 16 rows x 68
  const int seg = lane & 15, rq = lane >> 4;
  const int mrow_base = m0 + wr * 128;
  const int ncol_base = n0 + wc * 64;
  #pragma unroll
  for (int mf = 0; mf < 8; ++mf) {
    #pragma unroll
    for (int nf = 0; nf < 4; ++nf) {
      #pragma unroll
      for (int q = 0; q < 4; ++q)
        sb[(g * 4 + q) * 68 + nf * 16 + r16] = acc[mf][nf][q];
    }
    #pragma unroll
    for (int pz = 0; pz < 4; ++pz) {
      int row = rq + pz * 4;
      floatx4 v = *reinterpret_cast<const floatx4*>(&sb[row * 68 + seg * 4]);
      int m = mrow_base + mf * 16 + row;
      int n = ncol_base + seg * 4;
      if (n + 4 <= N) {
        __builtin_memcpy(&Cf[(size_t)m * N + n], &v, 16);
      } else {
        #pragma unroll
        for (int e = 0; e < 4; ++e)
          if (n + e < N) Cf[(size_t)m * N + n + e] = v[e];
      }
    }
  }
}

// ================= 128x128 BK=32 4-wave pipelined GEMM (qkv / fc) =================
// bf16 out. EPI: 3 +bias+gelu, 4 +bias. acc 64 AGPR + ~60 VGPR -> 4 blocks/CU.
// k_gemmp2-proven schedule: 2-phase, T2 swizzle pair, counted vmcnt(2), setprio.
template<int EPI>
__global__ __launch_bounds__(256, 4) void k_gemmq(
    const bf16* __restrict__ A, const bf16* __restrict__ Bt,
    const float* __restrict__ bias, bf16* __restrict__ Cb,
    int N, int K) {
  __shared__ __align__(16) bf16 smem[4 * 4096];   // A: 2x4096, B: 2x4096
  bf16* As = smem;
  bf16* Bs = smem + 2 * 4096;
  const int nwg = gridDim.x;   // 32 * (N/128), %8==0
  const int id = blockIdx.x;
  const int swz = (id & 7) * (nwg >> 3) + (id >> 3);
  const int m0 = (swz & 31) * 128;   // 32 m-tiles
  const int n0 = (swz >> 5) * 128;
  const int tid = threadIdx.x, lane = tid & 63, wave = tid >> 6;
  const int wr = wave >> 1, wc = wave & 1;   // 2M x 2N; wave tile 64x64
  const int g = lane >> 4, r16 = lane & 15;
  const int numK = K >> 5;
  const int wsl = wave * 512;

  const int srow = wave * 16 + (lane >> 2);            // 0..63
  const int scol = ((lane & 3) ^ ((lane >> 3) & 3)) * 8;   // T2 source permute
  const bf16* at  = A  + (size_t)(m0 + srow) * K + scol;
  const bf16* at1 = A  + (size_t)(m0 + srow + 64) * K + scol;
  const bf16* bt  = Bt + (size_t)(n0 + srow) * K + scol;
  const bf16* bt1 = Bt + (size_t)(n0 + srow + 64) * K + scol;
  const int sw = (g ^ ((r16 >> 1) & 3)) * 8;               // T2 read XOR
  const int a_off = (wr * 64 + r16) * 32 + sw;
  const int b_off = (wc * 64 + r16) * 32 + sw;

  floatx4 acc[4][4] = {};

#define STAq(s0, s1, pb) do { gload16((s0), As + (pb) * 4096 + wsl); \
                              gload16((s1), As + (pb) * 4096 + 2048 + wsl); } while (0)
#define STBq(s0, s1, pb) do { gload16((s0), Bs + (pb) * 4096 + wsl); \
                              gload16((s1), Bs + (pb) * 4096 + 2048 + wsl); } while (0)

  STBq(bt, bt1, 0);
  STAq(at, at1, 0);
  STBq(bt + 32, bt1 + 32, 1);
  asm volatile("s_waitcnt vmcnt(2)" ::: "memory");
  __builtin_amdgcn_s_barrier();

  for (int t = 0; t < numK; ++t) {
    const int p = t & 1, pn = p ^ 1;
    bf16x8 af[2], bfr[4];

    // ---- phase 0: mgroup 0 (acc[0..1]) ----
    #pragma unroll
    for (int j = 0; j < 4; ++j) bfr[j] = *(const bf16x8*)&Bs[p * 4096 + b_off + j * 512];
    #pragma unroll
    for (int i = 0; i < 2; ++i) af[i] = *(const bf16x8*)&As[p * 4096 + a_off + i * 512];
    if (t + 1 < numK) STAq(at + 32, at1 + 32, pn);
    __builtin_amdgcn_s_barrier();
    asm volatile("s_waitcnt lgkmcnt(0)" ::: "memory");
    __builtin_amdgcn_s_setprio(1);
    #pragma unroll
    for (int i = 0; i < 2; ++i)
      #pragma unroll
      for (int j = 0; j < 4; ++j)
        acc[i][j] = __builtin_amdgcn_mfma_f32_16x16x32_bf16(af[i], bfr[j], acc[i][j], 0, 0, 0);
    __builtin_amdgcn_s_setprio(0);
    __builtin_amdgcn_s_barrier();

    // ---- phase 1: mgroup 1 (acc[2..3]; B regs reused) ----
    #pragma unroll
    for (int i = 0; i < 2; ++i) af[i] = *(const bf16x8*)&As[p * 4096 + a_off + (i + 2) * 512];
    if (t + 2 < numK) STBq(bt + 64, bt1 + 64, p);
    __builtin_amdgcn_s_barrier();
    asm volatile("s_waitcnt lgkmcnt(0)" ::: "memory");
    __builtin_amdgcn_s_setprio(1);
    #pragma unroll
    for (int i = 0; i < 2; ++i)
      #pragma unroll
      for (int j = 0; j < 4; ++j)
        acc[i + 2][j] = __builtin_amdgcn_mfma_f32_16x16x32_bf16(af[i], bfr[j], acc[i + 2][j], 0, 0, 0);
    __builtin_amdgcn_s_setprio(0);
    if (t + 2 < numK) { asm volatile("s_waitcnt vmcnt(2)" ::: "memory"); }
    else              { asm volatile("s_waitcnt vmcnt(0)" ::: "memory"); }
    __builtin_amdgcn_s_barrier();

    at += 32; at1 += 32; bt += 32; bt1 += 32;
  }
#undef STAq
#undef STBq

  // epilogue: wave-private LDS transpose -> 16B bf16x8 stores (full cache lines)
  bf16* sb = smem + wave * 1152;   // 16 rows x 72 stride
  const int rr_rd = lane & 15, seg = lane >> 4;
  const int nb = n0 + wc * 64 + r16;
  float bv[4];
  #pragma unroll
  for (int j = 0; j < 4; ++j) bv[j] = bias[nb + j * 16];
  #pragma unroll
  for (int mf = 0; mf < 4; ++mf) {
    #pragma unroll
    for (int j = 0; j < 4; ++j) {
      #pragma unroll
      for (int q = 0; q < 4; ++q) {
        float v = acc[mf][j][q] + bv[j];
        if (EPI == 3) v = gelu_f(v);
        sb[(g * 4 + q) * 72 + j * 16 + r16] = (bf16)v;
      }
    }
    bf16x8 o0 = *(const bf16x8*)&sb[rr_rd * 72 + seg * 16];
    bf16x8 o1 = *(const bf16x8*)&sb[rr_rd * 72 + seg * 16 + 8];
    size_t orow = (size_t)(m0 + wr * 64 + mf * 16 + rr_rd) * N + (n0 + wc * 64 + seg * 16);
    *(bf16x8*)&Cb[orow] = o0;
    *(bf16x8*)&Cb[orow + 8] = o1;
  }
}

// ================= 64x128 BK=32 pipelined GEMM, 4 waves (proj / fcp) =================
// bias + residual in-place f32. acc 32 AGPR -> ~4 blocks/CU; grid 384.
__global__ __launch_bounds__(256, 4) void k_gemmp2(
    const bf16* __restrict__ A, const bf16* __restrict__ Bt,
    const float* __restrict__ bias, float* __restrict__ Cf,
    int N, int K) {
  __shared__ __align__(16) bf16 smem[2 * 2048 + 2 * 4096];   // A: 2x2048, B: 2x4096
  bf16* As = smem;
  bf16* Bs = smem + 2 * 2048;
  const int nwg = gridDim.x;   // 384, %8==0
  const int id = blockIdx.x;
  const int swz = (id & 7) * (nwg >> 3) + (id >> 3);
  const int m0 = (swz & 63) * 64;    // 64 m-tiles
  const int n0 = (swz >> 6) * 128;
  const int tid = threadIdx.x, lane = tid & 63, wave = tid >> 6;
  const int wr = wave >> 1, wc = wave & 1;   // 2M x 2N; wave tile 32x64
  const int g = lane >> 4, r16 = lane & 15;
  const int numK = K >> 5;
  const int wsl = wave * 512;

  const int srow = wave * 16 + (lane >> 2);            // 0..63
  const int scol = ((lane & 3) ^ ((lane >> 3) & 3)) * 8;
  const bf16* at  = A  + (size_t)(m0 + srow) * K + scol;
  const bf16* bt  = Bt + (size_t)(n0 + srow) * K + scol;
  const bf16* bt1 = Bt + (size_t)(n0 + srow + 64) * K + scol;
  const int sw = (g ^ ((r16 >> 1) & 3)) * 8;
  const int a_off = (wr * 32 + r16) * 32 + sw;
  const int b_off = (wc * 64 + r16) * 32 + sw;

  floatx4 acc[2][4] = {};

#define STAq(s0, pb) gload16((s0), As + (pb) * 2048 + wsl)
#define STBq(s0, s1, pb) do { gload16((s0), Bs + (pb) * 4096 + wsl); \
                              gload16((s1), Bs + (pb) * 4096 + 2048 + wsl); } while (0)

  STBq(bt, bt1, 0);
  STAq(at, 0);
  STBq(bt + 32, bt1 + 32, 1);
  asm volatile("s_waitcnt vmcnt(2)" ::: "memory");
  __builtin_amdgcn_s_barrier();

  for (int t = 0; t < numK; ++t) {
    const int p = t & 1, pn = p ^ 1;
    bf16x8 af, bfr[4];

    // ---- phase 0: mgroup 0 ----
    #pragma unroll
    for (int j = 0; j < 4; ++j) bfr[j] = *(const bf16x8*)&Bs[p * 4096 + b_off + j * 512];
    af = *(const bf16x8*)&As[p * 2048 + a_off];
    if (t + 1 < numK) STAq(at + 32, pn);
    __builtin_amdgcn_s_barrier();
    asm volatile("s_waitcnt lgkmcnt(0)" ::: "memory");
    __builtin_amdgcn_s_setprio(1);
    #pragma unroll
    for (int j = 0; j < 4; ++j)
      acc[0][j] = __builtin_amdgcn_mfma_f32_16x16x32_bf16(af, bfr[j], acc[0][j], 0, 0, 0);
    __builtin_amdgcn_s_setprio(0);
    __builtin_amdgcn_s_barrier();

    // ---- phase 1: mgroup 1 (B regs reused) ----
    af = *(const bf16x8*)&As[p * 2048 + a_off + 512];
    if (t + 2 < numK) STBq(bt + 64, bt1 + 64, p);
    __builtin_amdgcn_s_barrier();
    asm volatile("s_waitcnt lgkmcnt(0)" ::: "memory");
    __builtin_amdgcn_s_setprio(1);
    #pragma unroll
    for (int j = 0; j < 4; ++j)
      acc[1][j] = __builtin_amdgcn_mfma_f32_16x16x32_bf16(af, bfr[j], acc[1][j], 0, 0, 0);
    __builtin_amdgcn_s_setprio(0);
    if (t + 2 < numK) { asm volatile("s_waitcnt vmcnt(2)" ::: "memory"); }
    else              { asm volatile("s_waitcnt vmcnt(0)" ::: "memory"); }
    __builtin_amdgcn_s_barrier();

    at += 32; bt += 32; bt1 += 32;
  }
#undef STAq
#undef STBq

  // epilogue: bias + residual, scalar f32 (16 lanes = one aligned 64B line)
  const int mb = m0 + wr * 32 + g * 4;
  const int nb = n0 + wc * 64 + r16;
  #pragma unroll
  for (int j = 0; j < 4; ++j) {
    int n = nb + j * 16;
    float bv = bias[n];
    #pragma unroll
    for (int i = 0; i < 2; ++i) {
      #pragma unroll
      for (int q = 0; q < 4; ++q) {
        int m = mb + i * 16 + q;
        size_t o = (size_t)m * N + n;
        Cf[o] = Cf[o] + acc[i][j][q] + bv;
      }
    }
  }
}

// ---------------- V transpose: qkv_bf V-part -> vt[bh][d][t] bf16 ----------------
__global__ __launch_bounds__(256) void k_vtrans(const bf16* __restrict__ qkv, bf16* __restrict__ vt) {
  __shared__ bf16 tile[64][72];
  int bh = blockIdx.x, t0 = blockIdx.y * 64;
  int b = bh / HNUM, h = bh % HNUM;
  int tid = threadIdx.x;
  int r8 = tid >> 3, s8 = tid & 7;
  #pragma unroll
  for (int p = 0; p < 2; ++p) {
    int row = p * 32 + r8;
    uint4 v = *reinterpret_cast<const uint4*>(
        qkv + (size_t)(b * TDIM + t0 + row) * (3 * CDIM) + 2 * CDIM + h * 64 + s8 * 8);
    *reinterpret_cast<uint4*>(&tile[row][s8 * 8]) = v;
  }
  __syncthreads();
  int d = tid >> 2, q4 = tid & 3;
  #pragma unroll
  for (int half = 0; half < 2; ++half) {
    int t = q4 * 16 + half * 8;
    bf16x8 o;
    #pragma unroll
    for (int u = 0; u < 8; ++u) o[u] = tile[t + u][d];
    *reinterpret_cast<bf16x8*>(vt + (size_t)bh * (64 * TDIM) + (size_t)d * TDIM + t0 + t) = o;
  }
}

// ---------------- MFMA flash attention (QBLK=64, 4 waves — r8 proven) ----------------
__global__ __launch_bounds__(256) void k_attn(const bf16* __restrict__ qkv,
                                              const bf16* __restrict__ vt,
                                              bf16* __restrict__ y) {
  __shared__ __align__(16) bf16 Ks[64 * 64];
  __shared__ __align__(16) bf16 Vs[64 * 64];
  __shared__ __align__(16) bf16 Ps[64 * 64];
  const int bh = blockIdx.x, qt = blockIdx.y;
  const int b = bh / HNUM, h = bh % HNUM;
  const int tid = threadIdx.x, lane = tid & 63, wave = tid >> 6;
  const int g = lane >> 4, r16 = lane & 15;
  const int w16 = wave * 16;
  const int r8 = tid >> 3, s8 = tid & 7;

  bf16x8 qf[2];
  {
    const bf16* qsrc = qkv + (size_t)(b * TDIM + qt * 64 + w16 + r16) * (3 * CDIM) + h * 64 + g * 8;
    qf[0] = *reinterpret_cast<const bf16x8*>(qsrc);
    qf[1] = *reinterpret_cast<const bf16x8*>(qsrc + 32);
  }

  float m_r[4], l_r[4];
  floatx4 yacc[4] = {};
  #pragma unroll
  for (int q = 0; q < 4; ++q) { m_r[q] = -1e30f; l_r[q] = 0.f; }

  for (int kt = 0; kt <= qt; ++kt) {
    __syncthreads();
    #pragma unroll
    for (int p = 0; p < 2; ++p) {
      int row = p * 32 + r8;
      uint4 kv = *reinterpret_cast<const uint4*>(
          qkv + (size_t)(b * TDIM + kt * 64 + row) * (3 * CDIM) + CDIM + h * 64 + s8 * 8);
      *reinterpret_cast<uint4*>(&Ks[row * 64 + ((s8 ^ (row & 7)) * 8)]) = kv;
      uint4 vv = *reinterpret_cast<const uint4*>(
          vt + (size_t)bh * (64 * TDIM) + (size_t)row * TDIM + kt * 64 + s8 * 8);
      *reinterpret_cast<uint4*>(&Vs[row * 64 + ((s8 ^ (row & 7)) * 8)]) = vv;
    }
    __syncthreads();

    floatx4 sa[4] = {};
    #pragma unroll
    for (int c = 0; c < 2; ++c) {
      bf16x8 kf[4];
      #pragma unroll
      for (int j = 0; j < 4; ++j) {
        int krow = j * 16 + r16;
        kf[j] = *reinterpret_cast<const bf16x8*>(&Ks[krow * 64 + (((g + 4 * c) ^ (krow & 7)) * 8)]);
      }
      #pragma unroll
      for (int j = 0; j < 4; ++j)
        sa[j] = __builtin_amdgcn_mfma_f32_16x16x32_bf16(qf[c], kf[j], sa[j], 0, 0, 0);
    }

    const bool diag = (kt == qt);
    float p_v[4][4];
    #pragma unroll
    for (int q = 0; q < 4; ++q) {
      int qrow = w16 + g * 4 + q;
      float mx = -1e30f;
      #pragma unroll
      for (int j = 0; j < 4; ++j) {
        float s = sa[j][q] * 0.125f;
        if (diag && (r16 + j * 16) > qrow) s = -1e30f;
        p_v[j][q] = s;
        mx = fmaxf(mx, s);
      }
      #pragma unroll
      for (int o = 1; o < 16; o <<= 1) mx = fmaxf(mx, __shfl_xor(mx, o));
      float mnew = fmaxf(m_r[q], mx);
      float ps = 0.f;
      #pragma unroll
      for (int j = 0; j < 4; ++j) {
        float p = __expf(p_v[j][q] - mnew);
        p_v[j][q] = p;
        ps += p;
      }
      #pragma unroll
      for (int o = 1; o < 16; o <<= 1) ps += __shfl_xor(ps, o);
      float alpha = __expf(m_r[q] - mnew);
      m_r[q] = mnew;
      l_r[q] = l_r[q] * alpha + ps;
      #pragma unroll
      for (int j = 0; j < 4; ++j) yacc[j][q] *= alpha;
      #pragma unroll
      for (int j = 0; j < 4; ++j) {
        int col = r16 + j * 16;
        Ps[qrow * 64 + (col ^ ((qrow & 7) << 3))] = (bf16)p_v[j][q];
      }
    }

    #pragma unroll
    for (int ks = 0; ks < 2; ++ks) {
      int prow = w16 + r16;
      bf16x8 pa = *reinterpret_cast<const bf16x8*>(&Ps[prow * 64 + (((g + 4 * ks) ^ (prow & 7)) * 8)]);
      #pragma unroll
      for (int j = 0; j < 4; ++j) {
        int vrow = j * 16 + r16;
        bf16x8 vb = *reinterpret_cast<const bf16x8*>(&Vs[vrow * 64 + (((g + 4 * ks) ^ (vrow & 7)) * 8)]);
        yacc[j] = __builtin_amdgcn_mfma_f32_16x16x32_bf16(pa, vb, yacc[j], 0, 0, 0);
      }
    }
  }

  #pragma unroll
  for (int q = 0; q < 4; ++q) {
    float inv = 1.0f / l_r[q];
    int tok = b * TDIM + qt * 64 + w16 + g * 4 + q;
    #pragma unroll
    for (int j = 0; j < 4; ++j)
      y[(size_t)tok * CDIM + h * 64 + r16 + j * 16] = (bf16)(yacc[j][q] * inv);
  }
}

// ---------------- launcher ----------------
extern "C" void kernel_launch(void* const* d_in, const int* in_sizes, int n_in,
                              void* d_out, int out_size, void* d_ws, size_t ws_size,
                              hipStream_t stream) {
  (void)in_sizes; (void)n_in; (void)out_size;
  const int*   idx    = (const int*)  d_in[0];
  const float* wte    = (const float*)d_in[1];
  const float* wpe    = (const float*)d_in[2];
  const float* ln1_s  = (const float*)d_in[3];
  const float* ln1_b  = (const float*)d_in[4];
  const float* qkv_w  = (const float*)d_in[5];
  const float* qkv_b  = (const float*)d_in[6];
  const float* proj_w = (const float*)d_in[7];
  const float* proj_b = (const float*)d_in[8];
  const float* ln2_s  = (const float*)d_in[9];
  const float* ln2_b  = (const float*)d_in[10];
  const float* fc_w   = (const float*)d_in[11];
  const float* fc_b   = (const float*)d_in[12];
  const float* fcp_w  = (const float*)d_in[13];
  const float* fcp_b  = (const float*)d_in[14];
  const float* lnf_s  = (const float*)d_in[15];
  const float* lnf_b  = (const float*)d_in[16];
  float* logits = (float*)d_out;

  char* base = (char*)d_ws;
  size_t off = 0;
  auto alloc = [&](size_t bytes) -> void* {
    void* p = base + off;
    off += (bytes + 255) & ~(size_t)255;
    return p;
  };
  bf16*  wte_bf  = (bf16*) alloc((size_t)VDIM * CDIM * 2);   // keep FIRST (logits B-tail overreads land in ws)
  bf16*  wq_all  = (bf16*) alloc((size_t)LNUM * 3 * CDIM * CDIM * 2);
  bf16*  wp_all  = (bf16*) alloc((size_t)LNUM * CDIM * CDIM * 2);
  bf16*  wf_all  = (bf16*) alloc((size_t)LNUM * 4 * CDIM * CDIM * 2);
  bf16*  wfp_all = (bf16*) alloc((size_t)LNUM * 4 * CDIM * CDIM * 2);
  float* x       = (float*)alloc((size_t)NTOK * CDIM * 4);
  bf16*  hb      = (bf16*) alloc((size_t)NTOK * CDIM * 2);
  bf16*  qkv_bf  = (bf16*) alloc((size_t)NTOK * 3 * CDIM * 2);
  bf16*  vt      = (bf16*) alloc((size_t)BDIM * HNUM * 64 * TDIM * 2);
  bf16*  yb      = (bf16*) alloc((size_t)NTOK * CDIM * 2);
  bf16*  gb      = (bf16*) alloc((size_t)NTOK * 4 * CDIM * 2);
  if (off > ws_size) return;

  k_cvt_bf16<<<4096, 256, 0, stream>>>(wte, wte_bf, (long)VDIM * CDIM);
  k_trans_all<<<LNUM * TILES_LAYER, 256, 0, stream>>>(qkv_w, proj_w, fc_w, fcp_w,
                                                      wq_all, wp_all, wf_all, wfp_all);
  k_embed<<<NTOK, 256, 0, stream>>>(idx, wte, wpe, x);

  for (int l = 0; l < LNUM; ++l) {
    const bf16* wq  = wq_all  + (size_t)l * 3 * CDIM * CDIM;
    const bf16* wp  = wp_all  + (size_t)l * CDIM * CDIM;
    const bf16* wf  = wf_all  + (size_t)l * 4 * CDIM * CDIM;
    const bf16* wfp = wfp_all + (size_t)l * 4 * CDIM * CDIM;

    k_layernorm<<<NTOK, 256, 0, stream>>>(x, ln1_s + l*CDIM, ln1_b + l*CDIM, hb);
    k_gemmq<4><<<32 * 18, 256, 0, stream>>>(hb, wq, qkv_b + (size_t)l*3*CDIM, qkv_bf, 3*CDIM, CDIM);
    k_vtrans<<<dim3(BDIM*HNUM, TDIM/64), 256, 0, stream>>>(qkv_bf, vt);
    k_attn<<<dim3(BDIM*HNUM, TDIM/64), 256, 0, stream>>>(qkv_bf, vt, yb);
    k_gemmp2<<<64 * 6, 256, 0, stream>>>(yb, wp, proj_b + (size_t)l*CDIM, x, CDIM, CDIM);
    k_layernorm<<<NTOK, 256, 0, stream>>>(x, ln2_s + l*CDIM, ln2_b + l*CDIM, hb);
    k_gemmq<3><<<32 * 24, 256, 0, stream>>>(hb, wf, fc_b + (size_t)l*4*CDIM, gb, 4*CDIM, CDIM);
    k_gemmp2<<<64 * 6, 256, 0, stream>>>(gb, wfp, fcp_b + (size_t)l*CDIM, x, CDIM, 4*CDIM);
  }

  k_layernorm<<<NTOK, 256, 0, stream>>>(x, lnf_s, lnf_b, hb);
  int ntile = (VDIM + 255) / 256;  // 197; tail guarded, staging overreads stay in ws
  k_gemm_logits<<<16 * ntile, 512, 0, stream>>>(hb, wte_bf, logits, VDIM, CDIM);
}